// Round 7
// baseline (6282.657 us; speedup 1.0000x reference)
//
#include <hip/hip_runtime.h>
#include <hip/hip_bf16.h>
#include <math.h>

static constexpr int Bn = 8192;
static constexpr int Hn = 16384;
static constexpr int Dn = 1536;
static constexpr int KTOP = 64;
static constexpr int KE = 1536;             // single-pass bf16 GEMM K
static constexpr double EPSD = 1e-5;

// ---- workspace byte offsets (total use < 160 MB; <=306 MB proven safe) ----
static constexpr size_t MU_OFF  = 0;                 // float[8192]
static constexpr size_t STD_OFF = 32768;             // float[8192]
static constexpr size_t CNT_OFF = 98304;             // unsigned[8192]
static constexpr size_t NNZ_OFF = 131072;            // unsigned[1]
static constexpr size_t SUM_OFF = 131200;            // double[2]
static constexpr size_t MUD_OFF = 262144;            // double[8192]
static constexpr size_t RID_OFF = 327680;            // double[8192]
static constexpr size_t IDX_OFF = (size_t)1 << 20;   // int[8192*128]
static constexpr size_t VAL_OFF = (size_t)6 << 20;   // float[8192*128]
static constexpr size_t AP_OFF  = (size_t)16 << 20;  // bf16[8192*1536]  (25 MB)
static constexpr size_t BP_OFF  = (size_t)48 << 20;  // bf16[16384*1536] (50 MB)
static constexpr size_t WT_OFF  = (size_t)104 << 20; // bf16[16384*1536] (50 MB)

typedef __attribute__((ext_vector_type(8))) short short8;
typedef __attribute__((ext_vector_type(4))) float f32x4;

static __device__ __forceinline__ unsigned short f2bf(float f) {
    __hip_bfloat16 b = __float2bfloat16(f);
    return *reinterpret_cast<unsigned short*>(&b);
}
static __device__ __forceinline__ float bf2f(unsigned short u) {
    return __uint_as_float(((unsigned)u) << 16);
}
static __device__ __forceinline__ void gload_lds16(const void* g, void* l) {
    __builtin_amdgcn_global_load_lds(
        (const __attribute__((address_space(1))) unsigned int*)g,
        (__attribute__((address_space(3))) unsigned int*)l, 16, 0, 0);
}

__global__ void k_zero(unsigned* nnz, double* sums) {
    if (threadIdx.x == 0) { *nnz = 0u; sums[0] = 0.0; sums[1] = 0.0; }
}

// f64 row stats + write bf16 A row (xn - pre_bias) in one pass
__global__ __launch_bounds__(256) void k_rowstats(const float* __restrict__ x,
                                                  const float* __restrict__ pre_bias,
                                                  double* __restrict__ muD,
                                                  double* __restrict__ rinvD,
                                                  float* __restrict__ muF,
                                                  float* __restrict__ stdF,
                                                  unsigned short* __restrict__ Ap) {
    const int row = blockIdx.x;
    const int tid = threadIdx.x;
    const float* xr = x + (size_t)row * Dn;
    float v[6];
#pragma unroll
    for (int i = 0; i < 6; ++i) v[i] = xr[tid + 256 * i];
    double s = 0.0;
#pragma unroll
    for (int i = 0; i < 6; ++i) s += (double)v[i];
    __shared__ double redD[4];
    __shared__ double smu, srin;
#pragma unroll
    for (int o = 32; o > 0; o >>= 1) s += __shfl_down(s, o);
    if ((tid & 63) == 0) redD[tid >> 6] = s;
    __syncthreads();
    if (tid == 0) smu = (redD[0] + redD[1] + redD[2] + redD[3]) / (double)Dn;
    __syncthreads();
    const double m = smu;
    double q = 0.0;
#pragma unroll
    for (int i = 0; i < 6; ++i) { double d = (double)v[i] - m; q += d * d; }
#pragma unroll
    for (int o = 32; o > 0; o >>= 1) q += __shfl_down(q, o);
    if ((tid & 63) == 0) redD[tid >> 6] = q;
    __syncthreads();
    if (tid == 0) {
        double var = (redD[0] + redD[1] + redD[2] + redD[3]) / (double)(Dn - 1);
        double sd = sqrt(var);
        muD[row] = m;
        srin = 1.0 / (sd + EPSD);
        rinvD[row] = srin;
        muF[row] = (float)m;
        stdF[row] = (float)sd;
    }
    __syncthreads();
    const double ri = srin;
    unsigned short* ar = Ap + (size_t)row * KE;
#pragma unroll
    for (int i = 0; i < 6; ++i) {
        const int d = tid + i * 256;
        double a = ((double)v[i] - m) * ri - (double)pre_bias[d];
        ar[d] = f2bf((float)a);
    }
}

// Wenc f32 -> bf16
__global__ __launch_bounds__(256) void k_splitW(const float* __restrict__ Wenc,
                                                unsigned short* __restrict__ Bp) {
    const int row = blockIdx.x;
    const int tid = threadIdx.x;
    const float2* wr = (const float2*)(Wenc + (size_t)row * Dn);
    ushort2* br = (ushort2*)(Bp + (size_t)row * KE);
#pragma unroll
    for (int i = 0; i < 3; ++i) {
        float2 w = wr[tid + i * 256];
        ushort2 o; o.x = f2bf(w.x); o.y = f2bf(w.y);
        br[tid + i * 256] = o;
    }
}

// W_dec (D,H) f32 -> W_decT (H,D) bf16 in ws
__global__ __launch_bounds__(256) void k_transpose(const float* __restrict__ Wdec,
                                                   unsigned short* __restrict__ WdecT) {
    __shared__ float tile[32][33];
    const int h0 = blockIdx.x * 32;
    const int d0 = blockIdx.y * 32;
    const int tx = threadIdx.x & 31;
    const int ty = threadIdx.x >> 5;
#pragma unroll
    for (int r = 0; r < 4; ++r) {
        int d = ty + r * 8;
        tile[d][tx] = Wdec[(size_t)(d0 + d) * Hn + h0 + tx];
    }
    __syncthreads();
#pragma unroll
    for (int r = 0; r < 4; ++r) {
        int h = ty + r * 8;
        WdecT[(size_t)(h0 + h) * Dn + d0 + tx] = f2bf(tile[tx][h]);
    }
}

// bf16 MFMA GEMM, single pass K=1536: h = relu(A*B^T + lat_bias)
// 128x128 tile, 4 waves, BK=64, XOR bank-swizzle (round-6 verified),
// double-buffered LDS with one barrier per K-step (stage t+1 before compute t).
__global__ __launch_bounds__(256) void k_gemm(const unsigned short* __restrict__ Ap,
                                              const unsigned short* __restrict__ Bp,
                                              const float* __restrict__ lat_bias,
                                              float* __restrict__ hout) {
    __shared__ unsigned short As[2][128 * 64];   // 2 x 16 KB
    __shared__ unsigned short Bs[2][128 * 64];
    const int tid = threadIdx.x;
    const int lane = tid & 63;
    const int w = tid >> 6;
    const int wm = w >> 1, wn = w & 1;

    const int nwg = (Bn / 128) * (Hn / 128);          // 8192
    int swz = (blockIdx.x % 8) * (nwg / 8) + blockIdx.x / 8;
    int st = swz >> 6;
    int wi = swz & 63;
    int stm = st >> 4, stn = st & 15;
    const int bm = stm * 8 + (wi >> 3);
    const int bn = stn * 8 + (wi & 7);

    const int sr = tid >> 3;          // 0..31
    const int sp = tid & 7;           // 0..7
    const int ssl = sp ^ (sr & 7);    // inverse-swizzled source slot
    const size_t arow0 = (size_t)(bm * 128) * KE;
    const size_t brow0 = (size_t)(bn * 128) * KE;

    f32x4 acc[4][4];
#pragma unroll
    for (int i = 0; i < 4; ++i)
#pragma unroll
        for (int j = 0; j < 4; ++j) acc[i][j] = (f32x4){0.f, 0.f, 0.f, 0.f};

    constexpr int NT = KE / 64;       // 24
    // prologue: stage tile 0 into buffer 0
#pragma unroll
    for (int i = 0; i < 4; ++i) {
        gload_lds16(Ap + arow0 + (size_t)(i * 32 + sr) * KE + ssl * 8,
                    (char*)As[0] + i * 4096 + tid * 16);
        gload_lds16(Bp + brow0 + (size_t)(i * 32 + sr) * KE + ssl * 8,
                    (char*)Bs[0] + i * 4096 + tid * 16);
    }
    __syncthreads();

    int cur = 0;
    for (int t = 0; t < NT; ++t) {
        if (t + 1 < NT) {
            const int k1 = (t + 1) * 64;
#pragma unroll
            for (int i = 0; i < 4; ++i) {
                gload_lds16(Ap + arow0 + (size_t)(i * 32 + sr) * KE + k1 + ssl * 8,
                            (char*)As[cur ^ 1] + i * 4096 + tid * 16);
                gload_lds16(Bp + brow0 + (size_t)(i * 32 + sr) * KE + k1 + ssl * 8,
                            (char*)Bs[cur ^ 1] + i * 4096 + tid * 16);
            }
        }
        const unsigned short* Ab = As[cur];
        const unsigned short* Bb = Bs[cur];
#pragma unroll
        for (int kk = 0; kk < 2; ++kk) {
            short8 af[4], bf[4];
#pragma unroll
            for (int f = 0; f < 4; ++f) {
                const int ar = wm * 64 + f * 16 + (lane & 15);
                const int aslot = (kk * 4 + (lane >> 4)) ^ (ar & 7);
                af[f] = *(const short8*)((const char*)Ab + ar * 128 + aslot * 16);
                const int brr = wn * 64 + f * 16 + (lane & 15);
                const int bslot = (kk * 4 + (lane >> 4)) ^ (brr & 7);
                bf[f] = *(const short8*)((const char*)Bb + brr * 128 + bslot * 16);
            }
#pragma unroll
            for (int fi = 0; fi < 4; ++fi)
#pragma unroll
                for (int fj = 0; fj < 4; ++fj)
                    acc[fi][fj] = __builtin_amdgcn_mfma_f32_16x16x32_bf16(
                        af[fi], bf[fj], acc[fi][fj], 0, 0, 0);
        }
        __syncthreads();   // drains lgkm + vmcnt: next buffer ready, cur reusable
        cur ^= 1;
    }

    // epilogue: C/D map col=lane&15, row=(lane>>4)*4+reg  [m89]
    const int col = lane & 15;
    float biasv[4];
#pragma unroll
    for (int fj = 0; fj < 4; ++fj)
        biasv[fj] = lat_bias[bn * 128 + wn * 64 + fj * 16 + col];
#pragma unroll
    for (int fi = 0; fi < 4; ++fi) {
        const int gm0 = bm * 128 + wm * 64 + fi * 16 + (lane >> 4) * 4;
#pragma unroll
        for (int fj = 0; fj < 4; ++fj) {
            const int gn = bn * 128 + wn * 64 + fj * 16 + col;
#pragma unroll
            for (int r = 0; r < 4; ++r) {
                float vv = acc[fi][fj][r] + biasv[fj];
                hout[(size_t)(gm0 + r) * Hn + gn] = fmaxf(vv, 0.f);
            }
        }
    }
}

// fused: radix threshold + f64 band refine + in-place mask write + lists + stats
__global__ __launch_bounds__(256) void k_topk(float* __restrict__ h,
                                              const float* __restrict__ x,
                                              const float* __restrict__ Wenc,
                                              const float* __restrict__ pre_bias,
                                              const float* __restrict__ lat_bias,
                                              const double* __restrict__ muD,
                                              const double* __restrict__ rinvD,
                                              unsigned* __restrict__ counts,
                                              int* __restrict__ idx_list,
                                              float* __restrict__ val_list,
                                              unsigned* __restrict__ nnz_acc,
                                              double* __restrict__ sums) {
    const int row = blockIdx.x;
    const int tid = threadIdx.x;
    const int lane = tid & 63;
    const int wid = tid >> 6;
    float* hr = h + (size_t)row * Hn;
    float v[64];
#pragma unroll
    for (int j = 0; j < 64; ++j) v[j] = hr[j * 256 + tid];

    __shared__ unsigned hist[256];
    __shared__ unsigned sh_p, sh_r;
    unsigned prefix = 0, remain = KTOP;
    for (int shift = 24; shift >= 0; shift -= 8) {
        hist[tid] = 0;
        __syncthreads();
        const unsigned mhi = (shift == 24) ? 0u : (0xFFFFFFFFu << (shift + 8));
#pragma unroll
        for (int j = 0; j < 64; ++j) {
            unsigned key = __float_as_uint(v[j]);
            if (key != 0u && (key & mhi) == prefix)
                atomicAdd(&hist[(key >> shift) & 255u], 1u);
        }
        __syncthreads();
        if (tid == 0) {
            unsigned cum = 0; int sel = 0;
            for (int b = 255; b >= 0; --b) {
                unsigned c = hist[b];
                if (cum + c >= remain) { sel = b; break; }
                cum += c;
            }
            sh_p = prefix | ((unsigned)sel << shift);
            sh_r = remain - cum;
        }
        __syncthreads();
        prefix = sh_p; remain = sh_r;
        __syncthreads();
    }
    const float thr = __uint_as_float(prefix);

    const float DELTA = 0.02f;        // 18-sigma of 1-pass bf16 estimate error
    const float hi_t = thr + DELTA;
    const float lo_t = thr - DELTA;

    constexpr int MAXC = 128;
    __shared__ int s_g, s_c;
    __shared__ int cidx[MAXC];
    __shared__ double cvalD[MAXC];
    __shared__ float cref[MAXC];
    __shared__ unsigned char csel[MAXC];
    if (tid == 0) { s_g = 0; s_c = 0; }
    __syncthreads();
    int g_loc = 0;
#pragma unroll
    for (int j = 0; j < 64; ++j) {
        float val = v[j];
        if (val > hi_t) g_loc++;
        else if (val >= lo_t) {
            int p = atomicAdd(&s_c, 1);
            if (p < MAXC) cidx[p] = j * 256 + tid;
        }
    }
    if (g_loc) atomicAdd(&s_g, g_loc);
    __syncthreads();
    const int ec = (s_c < MAXC) ? s_c : MAXC;

    // exact f64 recompute of band candidates (wave 0)
    if (tid < 64) {
        const double rmu = muD[row];
        const double rin = rinvD[row];
        const float* xr = x + (size_t)row * Dn;
        for (int e = 0; e < ec; ++e) {
            const int feat = cidx[e];
            const float* wr = Wenc + (size_t)feat * Dn;
            double acc = 0.0;
            for (int d = tid; d < Dn; d += 64) {
                double xn = ((double)xr[d] - rmu) * rin - (double)pre_bias[d];
                acc = fma(xn, (double)wr[d], acc);
            }
#pragma unroll
            for (int o = 32; o > 0; o >>= 1) acc += __shfl_down(acc, o);
            if (tid == 0) {
                double hv = acc + (double)lat_bias[feat];
                cvalD[e] = hv;
                float hf = (float)hv;
                cref[e] = hf > 0.f ? hf : 0.f;
            }
        }
    }
    __syncthreads();
    // deterministic top-(64-g) among candidates by (value, lowest index)
    if (tid == 0) {
        const int need = KTOP - s_g;
        for (int e = 0; e < ec; ++e) csel[e] = 0;
        for (int it = 0; it < need && it < ec; ++it) {
            int best = -1; double bv = -1e300; int bidx = 1 << 30;
            for (int e = 0; e < ec; ++e) {
                if (csel[e]) continue;
                if (cvalD[e] > bv || (cvalD[e] == bv && cidx[e] < bidx)) {
                    bv = cvalD[e]; best = e; bidx = cidx[e];
                }
            }
            if (best >= 0) csel[best] = 1;
        }
    }
    __syncthreads();

    // keep mask (band-kept values substituted with exact cref)
    unsigned long long km = 0ull;
    int kc = 0;
#pragma unroll
    for (int j = 0; j < 64; ++j) {
        float val = v[j];
        bool k = false;
        if (val > hi_t) k = true;
        else if (val >= lo_t) {
            const int c = j * 256 + tid;
            for (int e = 0; e < ec; ++e)
                if (cidx[e] == c) {
                    k = (csel[e] != 0);
                    if (k) v[j] = cref[e];
                    break;
                }
        }
        if (k) { km |= (1ull << j); ++kc; }
    }
    // block prefix over per-thread counts (deterministic (tid,j) order)
    int p = kc;
#pragma unroll
    for (int o = 1; o < 64; o <<= 1) {
        int u = __shfl_up(p, o);
        if (lane >= o) p += u;
    }
    __shared__ int wtot[4], wbase[4];
    __shared__ unsigned stot;
    if (lane == 63) wtot[wid] = p;
    __syncthreads();
    if (tid == 0) {
        int b = 0;
        for (int ww = 0; ww < 4; ++ww) { wbase[ww] = b; b += wtot[ww]; }
        stot = (unsigned)b;
        counts[row] = (unsigned)(b < 128 ? b : 128);
    }
    __syncthreads();
    int pos = wbase[wid] + p - kc;

    float s1 = 0.f, s2 = 0.f;
#pragma unroll
    for (int j = 0; j < 64; ++j) {
        const bool k = (km >> j) & 1ull;
        const float ov = k ? v[j] : 0.f;
        hr[j * 256 + tid] = ov;
        if (k) {
            if (pos < 128) {
                idx_list[(size_t)row * 128 + pos] = j * 256 + tid;
                val_list[(size_t)row * 128 + pos] = v[j];
            }
            ++pos;
            s1 += v[j];
            s2 = fmaf(v[j], v[j], s2);
        }
    }
    __shared__ float r1[4], r2[4];
#pragma unroll
    for (int o = 32; o > 0; o >>= 1) {
        s1 += __shfl_down(s1, o);
        s2 += __shfl_down(s2, o);
    }
    if (lane == 0) { r1[wid] = s1; r2[wid] = s2; }
    __syncthreads();
    if (tid == 0) {
        atomicAdd(sums + 0, (double)(r1[0] + r1[1] + r1[2] + r1[3]));
        atomicAdd(sums + 1, (double)(r2[0] + r2[1] + r2[2] + r2[3]));
        atomicAdd(nnz_acc, stot);
    }
}

// sparse decoder, unroll-2 independent chains
__global__ __launch_bounds__(256) void k_decoder(const unsigned short* __restrict__ WdecT,
                                                 const float* __restrict__ pre_bias,
                                                 const float* __restrict__ muF,
                                                 const float* __restrict__ stdF,
                                                 const unsigned* __restrict__ counts,
                                                 const int* __restrict__ idx_list,
                                                 const float* __restrict__ val_list,
                                                 float* __restrict__ outr) {
    const int row = blockIdx.x;
    const int tid = threadIdx.x;
    const unsigned cnt = counts[row];
    __shared__ int sidx[128];
    __shared__ float sval[128];
    if (tid < (int)cnt) {
        sidx[tid] = idx_list[(size_t)row * 128 + tid];
        sval[tid] = val_list[(size_t)row * 128 + tid];
    }
    __syncthreads();
    float a0[3] = {0.f, 0.f, 0.f}, a1[3] = {0.f, 0.f, 0.f};
    float b0[3] = {0.f, 0.f, 0.f}, b1[3] = {0.f, 0.f, 0.f};
    unsigned j = 0;
    for (; j + 2 <= cnt; j += 2) {
        const ushort2* w0 = (const ushort2*)(WdecT + (size_t)sidx[j] * Dn);
        const ushort2* w1 = (const ushort2*)(WdecT + (size_t)sidx[j + 1] * Dn);
        const float v0 = sval[j], v1 = sval[j + 1];
#pragma unroll
        for (int i = 0; i < 3; ++i) {
            ushort2 p0 = w0[tid + i * 256];
            ushort2 p1 = w1[tid + i * 256];
            a0[i] = fmaf(v0, bf2f(p0.x), a0[i]);
            a1[i] = fmaf(v0, bf2f(p0.y), a1[i]);
            b0[i] = fmaf(v1, bf2f(p1.x), b0[i]);
            b1[i] = fmaf(v1, bf2f(p1.y), b1[i]);
        }
    }
    if (j < cnt) {
        const ushort2* w0 = (const ushort2*)(WdecT + (size_t)sidx[j] * Dn);
        const float v0 = sval[j];
#pragma unroll
        for (int i = 0; i < 3; ++i) {
            ushort2 p0 = w0[tid + i * 256];
            a0[i] = fmaf(v0, bf2f(p0.x), a0[i]);
            a1[i] = fmaf(v0, bf2f(p0.y), a1[i]);
        }
    }
    const float m_ = muF[row], s_ = stdF[row];
    float2* orow = (float2*)(outr + (size_t)row * Dn);
#pragma unroll
    for (int i = 0; i < 3; ++i) {
        const int p = tid + i * 256;
        float2 o;
        o.x = ((a0[i] + b0[i]) + pre_bias[2 * p + 0]) * s_ + m_;
        o.y = ((a1[i] + b1[i]) + pre_bias[2 * p + 1]) * s_ + m_;
        orow[p] = o;
    }
}

__global__ void k_final(const unsigned* __restrict__ nnz,
                        const double* __restrict__ sums,
                        float* __restrict__ out3) {
    if (threadIdx.x == 0) {
        const double N = (double)Bn * (double)Hn;
        const double nz = (double)(*nnz);
        const double sparsity = (N - nz) / N;
        const double mean = sums[0] / N;
        double var = (sums[1] - N * mean * mean) / (N - 1.0);
        if (var < 0.0) var = 0.0;
        out3[0] = (float)sparsity;
        out3[1] = (float)mean;
        out3[2] = (float)sqrt(var);
    }
}

extern "C" void kernel_launch(void* const* d_in, const int* in_sizes, int n_in,
                              void* d_out, int out_size, void* d_ws, size_t ws_size,
                              hipStream_t stream) {
    const float* x        = (const float*)d_in[0];
    const float* Wenc     = (const float*)d_in[1];
    const float* Wdec     = (const float*)d_in[2];
    const float* pre_bias = (const float*)d_in[3];
    const float* lat_bias = (const float*)d_in[4];

    char* ws = (char*)d_ws;
    float*          muF    = (float*)(ws + MU_OFF);
    float*          stdF   = (float*)(ws + STD_OFF);
    unsigned*       counts = (unsigned*)(ws + CNT_OFF);
    unsigned*       nnz    = (unsigned*)(ws + NNZ_OFF);
    double*         sums   = (double*)(ws + SUM_OFF);
    double*         muD    = (double*)(ws + MUD_OFF);
    double*         rinvD  = (double*)(ws + RID_OFF);
    int*            idxl   = (int*)(ws + IDX_OFF);
    float*          vall   = (float*)(ws + VAL_OFF);
    unsigned short* Ap     = (unsigned short*)(ws + AP_OFF);
    unsigned short* Bp     = (unsigned short*)(ws + BP_OFF);
    unsigned short* WdecT  = (unsigned short*)(ws + WT_OFF);

    float* out       = (float*)d_out;
    float* out_recon = out;
    float* out_h     = out + (size_t)Bn * Dn;
    float* out_sc    = out + (size_t)Bn * Dn + (size_t)Bn * Hn;
    float* hbuf      = out_h;   // f32 h staged in-place in the h_sparse region

    hipLaunchKernelGGL(k_zero, dim3(1), dim3(64), 0, stream, nnz, sums);
    hipLaunchKernelGGL(k_rowstats, dim3(Bn), dim3(256), 0, stream,
                       x, pre_bias, muD, rinvD, muF, stdF, Ap);
    hipLaunchKernelGGL(k_splitW, dim3(Hn), dim3(256), 0, stream, Wenc, Bp);
    hipLaunchKernelGGL(k_transpose, dim3(Hn / 32, Dn / 32), dim3(256), 0, stream, Wdec, WdecT);
    hipLaunchKernelGGL(k_gemm, dim3((Bn / 128) * (Hn / 128)), dim3(256), 0, stream,
                       Ap, Bp, lat_bias, hbuf);
    hipLaunchKernelGGL(k_topk, dim3(Bn), dim3(256), 0, stream,
                       hbuf, x, Wenc, pre_bias, lat_bias, muD, rinvD,
                       counts, idxl, vall, nnz, sums);
    hipLaunchKernelGGL(k_decoder, dim3(Bn), dim3(256), 0, stream,
                       WdecT, pre_bias, muF, stdF, counts, idxl, vall, out_recon);
    hipLaunchKernelGGL(k_final, dim3(1), dim3(64), 0, stream, nnz, sums, out_sc);
}

// Round 8
// 2171.902 us; speedup vs baseline: 2.8927x; 2.8927x over previous
//
#include <hip/hip_runtime.h>
#include <hip/hip_bf16.h>
#include <math.h>

static constexpr int Bn = 8192;
static constexpr int Hn = 16384;
static constexpr int Dn = 1536;
static constexpr int KTOP = 64;
static constexpr int KE = 1536;             // single-pass bf16 GEMM K
static constexpr double EPSD = 1e-5;

// ---- workspace byte offsets ----
static constexpr size_t MU_OFF  = 0;                 // float[8192]
static constexpr size_t STD_OFF = 32768;             // float[8192]
static constexpr size_t THR_OFF = 65536;             // float[8192]
static constexpr size_t CNT_OFF = 98304;             // unsigned[8192]
static constexpr size_t NNZ_OFF = 131072;            // unsigned[1]
static constexpr size_t SUM_OFF = 131200;            // double[2]
static constexpr size_t MUD_OFF = 262144;            // double[8192]
static constexpr size_t RID_OFF = 327680;            // double[8192]
static constexpr size_t IDX_OFF = (size_t)1 << 20;   // int[8192*128]
static constexpr size_t VAL_OFF = (size_t)6 << 20;   // float[8192*128]
static constexpr size_t AP_OFF  = (size_t)16 << 20;  // bf16[8192*1536]  (25 MB)
static constexpr size_t BP_OFF  = (size_t)48 << 20;  // bf16[16384*1536] (50 MB)
static constexpr size_t WT_OFF  = (size_t)104 << 20; // bf16[16384*1536] (50 MB)

typedef __attribute__((ext_vector_type(8))) short short8;
typedef __attribute__((ext_vector_type(4))) float f32x4;

static __device__ __forceinline__ unsigned short f2bf(float f) {
    __hip_bfloat16 b = __float2bfloat16(f);
    return *reinterpret_cast<unsigned short*>(&b);
}
static __device__ __forceinline__ float bf2f(unsigned short u) {
    return __uint_as_float(((unsigned)u) << 16);
}
static __device__ __forceinline__ void gload_lds16(const void* g, void* l) {
    __builtin_amdgcn_global_load_lds(
        (const __attribute__((address_space(1))) unsigned int*)g,
        (__attribute__((address_space(3))) unsigned int*)l, 16, 0, 0);
}

__global__ void k_zero(unsigned* nnz, double* sums) {
    if (threadIdx.x == 0) { *nnz = 0u; sums[0] = 0.0; sums[1] = 0.0; }
}

// f64 row stats + write bf16 A row (xn - pre_bias) in one pass
__global__ __launch_bounds__(256) void k_rowstats(const float* __restrict__ x,
                                                  const float* __restrict__ pre_bias,
                                                  double* __restrict__ muD,
                                                  double* __restrict__ rinvD,
                                                  float* __restrict__ muF,
                                                  float* __restrict__ stdF,
                                                  unsigned short* __restrict__ Ap) {
    const int row = blockIdx.x;
    const int tid = threadIdx.x;
    const float* xr = x + (size_t)row * Dn;
    float v[6];
#pragma unroll
    for (int i = 0; i < 6; ++i) v[i] = xr[tid + 256 * i];
    double s = 0.0;
#pragma unroll
    for (int i = 0; i < 6; ++i) s += (double)v[i];
    __shared__ double redD[4];
    __shared__ double smu, srin;
#pragma unroll
    for (int o = 32; o > 0; o >>= 1) s += __shfl_down(s, o);
    if ((tid & 63) == 0) redD[tid >> 6] = s;
    __syncthreads();
    if (tid == 0) smu = (redD[0] + redD[1] + redD[2] + redD[3]) / (double)Dn;
    __syncthreads();
    const double m = smu;
    double q = 0.0;
#pragma unroll
    for (int i = 0; i < 6; ++i) { double d = (double)v[i] - m; q += d * d; }
#pragma unroll
    for (int o = 32; o > 0; o >>= 1) q += __shfl_down(q, o);
    if ((tid & 63) == 0) redD[tid >> 6] = q;
    __syncthreads();
    if (tid == 0) {
        double var = (redD[0] + redD[1] + redD[2] + redD[3]) / (double)(Dn - 1);
        double sd = sqrt(var);
        muD[row] = m;
        srin = 1.0 / (sd + EPSD);
        rinvD[row] = srin;
        muF[row] = (float)m;
        stdF[row] = (float)sd;
    }
    __syncthreads();
    const double ri = srin;
    unsigned short* ar = Ap + (size_t)row * KE;
#pragma unroll
    for (int i = 0; i < 6; ++i) {
        const int d = tid + i * 256;
        double a = ((double)v[i] - m) * ri - (double)pre_bias[d];
        ar[d] = f2bf((float)a);
    }
}

// Wenc f32 -> bf16
__global__ __launch_bounds__(256) void k_splitW(const float* __restrict__ Wenc,
                                                unsigned short* __restrict__ Bp) {
    const int row = blockIdx.x;
    const int tid = threadIdx.x;
    const float2* wr = (const float2*)(Wenc + (size_t)row * Dn);
    ushort2* br = (ushort2*)(Bp + (size_t)row * KE);
#pragma unroll
    for (int i = 0; i < 3; ++i) {
        float2 w = wr[tid + i * 256];
        ushort2 o; o.x = f2bf(w.x); o.y = f2bf(w.y);
        br[tid + i * 256] = o;
    }
}

// W_dec (D,H) f32 -> W_decT (H,D) bf16 in ws
__global__ __launch_bounds__(256) void k_transpose(const float* __restrict__ Wdec,
                                                   unsigned short* __restrict__ WdecT) {
    __shared__ float tile[32][33];
    const int h0 = blockIdx.x * 32;
    const int d0 = blockIdx.y * 32;
    const int tx = threadIdx.x & 31;
    const int ty = threadIdx.x >> 5;
#pragma unroll
    for (int r = 0; r < 4; ++r) {
        int d = ty + r * 8;
        tile[d][tx] = Wdec[(size_t)(d0 + d) * Hn + h0 + tx];
    }
    __syncthreads();
#pragma unroll
    for (int r = 0; r < 4; ++r) {
        int h = ty + r * 8;
        WdecT[(size_t)(h0 + h) * Dn + d0 + tx] = f2bf(tile[tx][h]);
    }
}

// bf16 MFMA GEMM, single pass K=1536 (round-7 verified, dbuf + XOR swizzle)
__global__ __launch_bounds__(256) void k_gemm(const unsigned short* __restrict__ Ap,
                                              const unsigned short* __restrict__ Bp,
                                              const float* __restrict__ lat_bias,
                                              float* __restrict__ hout) {
    __shared__ unsigned short As[2][128 * 64];
    __shared__ unsigned short Bs[2][128 * 64];
    const int tid = threadIdx.x;
    const int lane = tid & 63;
    const int w = tid >> 6;
    const int wm = w >> 1, wn = w & 1;

    const int nwg = (Bn / 128) * (Hn / 128);          // 8192
    int swz = (blockIdx.x % 8) * (nwg / 8) + blockIdx.x / 8;
    int st = swz >> 6;
    int wi = swz & 63;
    int stm = st >> 4, stn = st & 15;
    const int bm = stm * 8 + (wi >> 3);
    const int bn = stn * 8 + (wi & 7);

    const int sr = tid >> 3;
    const int sp = tid & 7;
    const int ssl = sp ^ (sr & 7);
    const size_t arow0 = (size_t)(bm * 128) * KE;
    const size_t brow0 = (size_t)(bn * 128) * KE;

    f32x4 acc[4][4];
#pragma unroll
    for (int i = 0; i < 4; ++i)
#pragma unroll
        for (int j = 0; j < 4; ++j) acc[i][j] = (f32x4){0.f, 0.f, 0.f, 0.f};

    constexpr int NT = KE / 64;       // 24
#pragma unroll
    for (int i = 0; i < 4; ++i) {
        gload_lds16(Ap + arow0 + (size_t)(i * 32 + sr) * KE + ssl * 8,
                    (char*)As[0] + i * 4096 + tid * 16);
        gload_lds16(Bp + brow0 + (size_t)(i * 32 + sr) * KE + ssl * 8,
                    (char*)Bs[0] + i * 4096 + tid * 16);
    }
    __syncthreads();

    int cur = 0;
    for (int t = 0; t < NT; ++t) {
        if (t + 1 < NT) {
            const int k1 = (t + 1) * 64;
#pragma unroll
            for (int i = 0; i < 4; ++i) {
                gload_lds16(Ap + arow0 + (size_t)(i * 32 + sr) * KE + k1 + ssl * 8,
                            (char*)As[cur ^ 1] + i * 4096 + tid * 16);
                gload_lds16(Bp + brow0 + (size_t)(i * 32 + sr) * KE + k1 + ssl * 8,
                            (char*)Bs[cur ^ 1] + i * 4096 + tid * 16);
            }
        }
        const unsigned short* Ab = As[cur];
        const unsigned short* Bb = Bs[cur];
#pragma unroll
        for (int kk = 0; kk < 2; ++kk) {
            short8 af[4], bf[4];
#pragma unroll
            for (int f = 0; f < 4; ++f) {
                const int ar = wm * 64 + f * 16 + (lane & 15);
                const int aslot = (kk * 4 + (lane >> 4)) ^ (ar & 7);
                af[f] = *(const short8*)((const char*)Ab + ar * 128 + aslot * 16);
                const int brr = wn * 64 + f * 16 + (lane & 15);
                const int bslot = (kk * 4 + (lane >> 4)) ^ (brr & 7);
                bf[f] = *(const short8*)((const char*)Bb + brr * 128 + bslot * 16);
            }
#pragma unroll
            for (int fi = 0; fi < 4; ++fi)
#pragma unroll
                for (int fj = 0; fj < 4; ++fj)
                    acc[fi][fj] = __builtin_amdgcn_mfma_f32_16x16x32_bf16(
                        af[fi], bf[fj], acc[fi][fj], 0, 0, 0);
        }
        __syncthreads();
        cur ^= 1;
    }

    const int col = lane & 15;
    float biasv[4];
#pragma unroll
    for (int fj = 0; fj < 4; ++fj)
        biasv[fj] = lat_bias[bn * 128 + wn * 64 + fj * 16 + col];
#pragma unroll
    for (int fi = 0; fi < 4; ++fi) {
        const int gm0 = bm * 128 + wm * 64 + fi * 16 + (lane >> 4) * 4;
#pragma unroll
        for (int fj = 0; fj < 4; ++fj) {
            const int gn = bn * 128 + wn * 64 + fj * 16 + col;
#pragma unroll
            for (int r = 0; r < 4; ++r) {
                float vv = acc[fi][fj][r] + biasv[fj];
                hout[(size_t)(gm0 + r) * Hn + gn] = fmaxf(vv, 0.f);
            }
        }
    }
}

// radix threshold only (rounds 4-6 proven shape): thr = 64th largest of approx h
__global__ __launch_bounds__(256) void k_thresh(const float* __restrict__ h,
                                                float* __restrict__ thr_out) {
    const int row = blockIdx.x;
    const int tid = threadIdx.x;
    const float* hr = h + (size_t)row * Hn;
    float v[64];
#pragma unroll
    for (int j = 0; j < 64; ++j) v[j] = hr[j * 256 + tid];

    __shared__ unsigned hist[256];
    __shared__ unsigned sh_p, sh_r;
    unsigned prefix = 0, remain = KTOP;
    for (int shift = 24; shift >= 0; shift -= 8) {
        hist[tid] = 0;
        __syncthreads();
        const unsigned mhi = (shift == 24) ? 0u : (0xFFFFFFFFu << (shift + 8));
#pragma unroll
        for (int j = 0; j < 64; ++j) {
            unsigned key = __float_as_uint(v[j]);
            if (key != 0u && (key & mhi) == prefix)
                atomicAdd(&hist[(key >> shift) & 255u], 1u);
        }
        __syncthreads();
        if (tid == 0) {
            unsigned cum = 0; int sel = 0;
            for (int b = 255; b >= 0; --b) {
                unsigned c = hist[b];
                if (cum + c >= remain) { sel = b; break; }
                cum += c;
            }
            sh_p = prefix | ((unsigned)sel << shift);
            sh_r = remain - cum;
        }
        __syncthreads();
        prefix = sh_p; remain = sh_r;
        __syncthreads();
    }
    if (tid == 0) thr_out[row] = __uint_as_float(prefix);
}

// band classify + wave-parallel f64 refine + deterministic selection + compaction
__global__ __launch_bounds__(256) void k_select(const float* __restrict__ h,
                                                const float* __restrict__ x,
                                                const float* __restrict__ Wenc,
                                                const float* __restrict__ pre_bias,
                                                const float* __restrict__ lat_bias,
                                                const double* __restrict__ muD,
                                                const double* __restrict__ rinvD,
                                                const float* __restrict__ thr_in,
                                                unsigned* __restrict__ counts,
                                                int* __restrict__ idx_list,
                                                float* __restrict__ val_list) {
    const int row = blockIdx.x;
    const int tid = threadIdx.x;
    const int lane = tid & 63;
    const int wid = tid >> 6;
    const float* hr = h + (size_t)row * Hn;
    const float thr = thr_in[row];
    const float DELTA = 0.02f;        // 18-sigma of 1-pass bf16 estimate error
    const float hi_t = thr + DELTA;
    const float lo_t = thr - DELTA;

    constexpr int MAXC = 128;
    __shared__ int s_g, s_c;
    __shared__ int cidx[MAXC];
    __shared__ double cvalD[MAXC];
    __shared__ float cref[MAXC];
    __shared__ unsigned char csel[MAXC];
    if (tid == 0) { s_g = 0; s_c = 0; }
    __syncthreads();
    int g_loc = 0;
    for (int j = 0; j < 64; ++j) {
        float val = hr[j * 256 + tid];
        if (val > hi_t) g_loc++;
        else if (val >= lo_t) {
            int p = atomicAdd(&s_c, 1);
            if (p < MAXC) cidx[p] = j * 256 + tid;
        }
    }
    if (g_loc) atomicAdd(&s_g, g_loc);
    __syncthreads();
    const int ec = (s_c < MAXC) ? s_c : MAXC;

    // f64 recompute, wave-parallel: wave w handles e = w, w+4, ...
    {
        const double rmu = muD[row];
        const double rin = rinvD[row];
        const float* xr = x + (size_t)row * Dn;
        for (int e = wid; e < ec; e += 4) {
            const int feat = cidx[e];
            const float* wr = Wenc + (size_t)feat * Dn;
            double acc = 0.0;
            for (int d = lane; d < Dn; d += 64) {
                double xn = ((double)xr[d] - rmu) * rin - (double)pre_bias[d];
                acc = fma(xn, (double)wr[d], acc);
            }
#pragma unroll
            for (int o = 32; o > 0; o >>= 1) acc += __shfl_down(acc, o);
            if (lane == 0) {
                double hv = acc + (double)lat_bias[feat];
                cvalD[e] = hv;
                float hf = (float)hv;
                cref[e] = hf > 0.f ? hf : 0.f;
            }
        }
    }
    __syncthreads();
    // deterministic top-(64-g) among candidates by (value, lowest index)
    if (tid == 0) {
        const int need = KTOP - s_g;
        for (int e = 0; e < ec; ++e) csel[e] = 0;
        for (int it = 0; it < need && it < ec; ++it) {
            int best = -1; double bv = -1e300; int bidx = 1 << 30;
            for (int e = 0; e < ec; ++e) {
                if (csel[e]) continue;
                if (cvalD[e] > bv || (cvalD[e] == bv && cidx[e] < bidx)) {
                    bv = cvalD[e]; best = e; bidx = cidx[e];
                }
            }
            if (best >= 0) csel[best] = 1;
        }
    }
    __syncthreads();

    // wave-0 ballot compaction, index-ordered (rounds 4-6 proven); hr is L2-hot
    if (tid < 64) {
        unsigned cnt = 0;
        for (int base = 0; base < Hn; base += 64) {
            const int f = base + tid;
            float val = hr[f];
            bool keep;
            float sv = val;
            if (val >= lo_t && val <= hi_t) {
                keep = false;
                for (int e = 0; e < ec; ++e)
                    if (cidx[e] == f) { keep = (csel[e] != 0); sv = cref[e]; break; }
            } else {
                keep = (val > hi_t);
            }
            unsigned long long bm = __ballot(keep);
            unsigned pre = (unsigned)__popcll(bm & ((1ull << tid) - 1ull));
            unsigned pos = cnt + pre;
            if (keep && pos < 128u) {
                idx_list[(size_t)row * 128 + pos] = f;
                val_list[(size_t)row * 128 + pos] = sv;
            }
            cnt += (unsigned)__popcll(bm);
        }
        if (tid == 0) counts[row] = cnt < 128u ? cnt : 128u;
    }
}

// zero h_sparse region, scatter kept values, accumulate stats (round-6 proven)
__global__ __launch_bounds__(256) void k_hwrite(const unsigned* __restrict__ counts,
                                                const int* __restrict__ idx_list,
                                                const float* __restrict__ val_list,
                                                float* __restrict__ outh,
                                                unsigned* __restrict__ nnz_acc,
                                                double* __restrict__ sums) {
    const int row = blockIdx.x;
    const int tid = threadIdx.x;
    const unsigned cnt = counts[row];
    float* orow = outh + (size_t)row * Hn;
    float4* orow16 = (float4*)orow;
    const float4 z = {0.f, 0.f, 0.f, 0.f};
#pragma unroll
    for (int i = 0; i < 16; ++i) orow16[tid + i * 256] = z;
    __syncthreads();
    float val = 0.f;
    if (tid < (int)cnt) {
        int idx = idx_list[(size_t)row * 128 + tid];
        val = val_list[(size_t)row * 128 + tid];
        orow[idx] = val;
    }
    float s1 = val, s2 = val * val;
    __shared__ float r1[4], r2[4];
#pragma unroll
    for (int o = 32; o > 0; o >>= 1) {
        s1 += __shfl_down(s1, o);
        s2 += __shfl_down(s2, o);
    }
    if ((tid & 63) == 0) { r1[tid >> 6] = s1; r2[tid >> 6] = s2; }
    __syncthreads();
    if (tid == 0) {
        atomicAdd(sums + 0, (double)(r1[0] + r1[1] + r1[2] + r1[3]));
        atomicAdd(sums + 1, (double)(r2[0] + r2[1] + r2[2] + r2[3]));
        atomicAdd(nnz_acc, cnt);
    }
}

// sparse decoder, unroll-2 independent chains
__global__ __launch_bounds__(256) void k_decoder(const unsigned short* __restrict__ WdecT,
                                                 const float* __restrict__ pre_bias,
                                                 const float* __restrict__ muF,
                                                 const float* __restrict__ stdF,
                                                 const unsigned* __restrict__ counts,
                                                 const int* __restrict__ idx_list,
                                                 const float* __restrict__ val_list,
                                                 float* __restrict__ outr) {
    const int row = blockIdx.x;
    const int tid = threadIdx.x;
    const unsigned cnt = counts[row];
    __shared__ int sidx[128];
    __shared__ float sval[128];
    if (tid < (int)cnt) {
        sidx[tid] = idx_list[(size_t)row * 128 + tid];
        sval[tid] = val_list[(size_t)row * 128 + tid];
    }
    __syncthreads();
    float a0[3] = {0.f, 0.f, 0.f}, a1[3] = {0.f, 0.f, 0.f};
    float b0[3] = {0.f, 0.f, 0.f}, b1[3] = {0.f, 0.f, 0.f};
    unsigned j = 0;
    for (; j + 2 <= cnt; j += 2) {
        const ushort2* w0 = (const ushort2*)(WdecT + (size_t)sidx[j] * Dn);
        const ushort2* w1 = (const ushort2*)(WdecT + (size_t)sidx[j + 1] * Dn);
        const float v0 = sval[j], v1 = sval[j + 1];
#pragma unroll
        for (int i = 0; i < 3; ++i) {
            ushort2 p0 = w0[tid + i * 256];
            ushort2 p1 = w1[tid + i * 256];
            a0[i] = fmaf(v0, bf2f(p0.x), a0[i]);
            a1[i] = fmaf(v0, bf2f(p0.y), a1[i]);
            b0[i] = fmaf(v1, bf2f(p1.x), b0[i]);
            b1[i] = fmaf(v1, bf2f(p1.y), b1[i]);
        }
    }
    if (j < cnt) {
        const ushort2* w0 = (const ushort2*)(WdecT + (size_t)sidx[j] * Dn);
        const float v0 = sval[j];
#pragma unroll
        for (int i = 0; i < 3; ++i) {
            ushort2 p0 = w0[tid + i * 256];
            a0[i] = fmaf(v0, bf2f(p0.x), a0[i]);
            a1[i] = fmaf(v0, bf2f(p0.y), a1[i]);
        }
    }
    const float m_ = muF[row], s_ = stdF[row];
    float2* orow = (float2*)(outr + (size_t)row * Dn);
#pragma unroll
    for (int i = 0; i < 3; ++i) {
        const int p = tid + i * 256;
        float2 o;
        o.x = ((a0[i] + b0[i]) + pre_bias[2 * p + 0]) * s_ + m_;
        o.y = ((a1[i] + b1[i]) + pre_bias[2 * p + 1]) * s_ + m_;
        orow[p] = o;
    }
}

__global__ void k_final(const unsigned* __restrict__ nnz,
                        const double* __restrict__ sums,
                        float* __restrict__ out3) {
    if (threadIdx.x == 0) {
        const double N = (double)Bn * (double)Hn;
        const double nz = (double)(*nnz);
        const double sparsity = (N - nz) / N;
        const double mean = sums[0] / N;
        double var = (sums[1] - N * mean * mean) / (N - 1.0);
        if (var < 0.0) var = 0.0;
        out3[0] = (float)sparsity;
        out3[1] = (float)mean;
        out3[2] = (float)sqrt(var);
    }
}

extern "C" void kernel_launch(void* const* d_in, const int* in_sizes, int n_in,
                              void* d_out, int out_size, void* d_ws, size_t ws_size,
                              hipStream_t stream) {
    const float* x        = (const float*)d_in[0];
    const float* Wenc     = (const float*)d_in[1];
    const float* Wdec     = (const float*)d_in[2];
    const float* pre_bias = (const float*)d_in[3];
    const float* lat_bias = (const float*)d_in[4];

    char* ws = (char*)d_ws;
    float*          muF    = (float*)(ws + MU_OFF);
    float*          stdF   = (float*)(ws + STD_OFF);
    float*          thr    = (float*)(ws + THR_OFF);
    unsigned*       counts = (unsigned*)(ws + CNT_OFF);
    unsigned*       nnz    = (unsigned*)(ws + NNZ_OFF);
    double*         sums   = (double*)(ws + SUM_OFF);
    double*         muD    = (double*)(ws + MUD_OFF);
    double*         rinvD  = (double*)(ws + RID_OFF);
    int*            idxl   = (int*)(ws + IDX_OFF);
    float*          vall   = (float*)(ws + VAL_OFF);
    unsigned short* Ap     = (unsigned short*)(ws + AP_OFF);
    unsigned short* Bp     = (unsigned short*)(ws + BP_OFF);
    unsigned short* WdecT  = (unsigned short*)(ws + WT_OFF);

    float* out       = (float*)d_out;
    float* out_recon = out;
    float* out_h     = out + (size_t)Bn * Dn;
    float* out_sc    = out + (size_t)Bn * Dn + (size_t)Bn * Hn;
    float* hbuf      = out_h;   // f32 h staged in-place in the h_sparse region

    hipLaunchKernelGGL(k_zero, dim3(1), dim3(64), 0, stream, nnz, sums);
    hipLaunchKernelGGL(k_rowstats, dim3(Bn), dim3(256), 0, stream,
                       x, pre_bias, muD, rinvD, muF, stdF, Ap);
    hipLaunchKernelGGL(k_splitW, dim3(Hn), dim3(256), 0, stream, Wenc, Bp);
    hipLaunchKernelGGL(k_transpose, dim3(Hn / 32, Dn / 32), dim3(256), 0, stream, Wdec, WdecT);
    hipLaunchKernelGGL(k_gemm, dim3((Bn / 128) * (Hn / 128)), dim3(256), 0, stream,
                       Ap, Bp, lat_bias, hbuf);
    hipLaunchKernelGGL(k_thresh, dim3(Bn), dim3(256), 0, stream, hbuf, thr);
    hipLaunchKernelGGL(k_select, dim3(Bn), dim3(256), 0, stream,
                       hbuf, x, Wenc, pre_bias, lat_bias, muD, rinvD, thr,
                       counts, idxl, vall);
    hipLaunchKernelGGL(k_hwrite, dim3(Bn), dim3(256), 0, stream,
                       counts, idxl, vall, out_h, nnz, sums);
    hipLaunchKernelGGL(k_decoder, dim3(Bn), dim3(256), 0, stream,
                       WdecT, pre_bias, muF, stdF, counts, idxl, vall, out_recon);
    hipLaunchKernelGGL(k_final, dim3(1), dim3(64), 0, stream, nnz, sums, out_sc);
}

// Round 9
// 1732.895 us; speedup vs baseline: 3.6255x; 1.2533x over previous
//
#include <hip/hip_runtime.h>
#include <hip/hip_bf16.h>
#include <math.h>

static constexpr int Bn = 8192;
static constexpr int Hn = 16384;
static constexpr int Dn = 1536;
static constexpr int KTOP = 64;
static constexpr int KE = 1536;             // single-pass bf16 GEMM K
static constexpr double EPSD = 1e-5;

// ---- workspace byte offsets (peak ~428 MB; >=672 MB proven mapped, r1/r2) ----
static constexpr size_t MU_OFF  = 0;                 // float[8192]
static constexpr size_t STD_OFF = 32768;             // float[8192]
static constexpr size_t THR_OFF = 65536;             // float[8192]
static constexpr size_t CNT_OFF = 98304;             // unsigned[8192]
static constexpr size_t NNZ_OFF = 131072;            // unsigned[1]
static constexpr size_t SUM_OFF = 131200;            // double[2]
static constexpr size_t MUD_OFF = 262144;            // double[8192]
static constexpr size_t RID_OFF = 327680;            // double[8192]
static constexpr size_t IDX_OFF = (size_t)1 << 20;   // int[8192*128]
static constexpr size_t VAL_OFF = (size_t)6 << 20;   // float[8192*128]
static constexpr size_t AP_OFF  = (size_t)16 << 20;  // bf16[8192*1536]  (25 MB)
static constexpr size_t BP_OFF  = (size_t)48 << 20;  // bf16[16384*1536] (50 MB)
static constexpr size_t WT_OFF  = (size_t)104 << 20; // bf16[16384*1536] (50 MB)
static constexpr size_t H16_OFF = (size_t)160 << 20; // bf16[8192*16384] (268 MB)

typedef __attribute__((ext_vector_type(8))) short short8;
typedef __attribute__((ext_vector_type(4))) float f32x4;

static __device__ __forceinline__ unsigned short f2bf(float f) {
    __hip_bfloat16 b = __float2bfloat16(f);
    return *reinterpret_cast<unsigned short*>(&b);
}
static __device__ __forceinline__ float bf2f(unsigned short u) {
    return __uint_as_float(((unsigned)u) << 16);
}
static __device__ __forceinline__ void gload_lds16(const void* g, void* l) {
    __builtin_amdgcn_global_load_lds(
        (const __attribute__((address_space(1))) unsigned int*)g,
        (__attribute__((address_space(3))) unsigned int*)l, 16, 0, 0);
}

__global__ void k_zero(unsigned* nnz, double* sums) {
    if (threadIdx.x == 0) { *nnz = 0u; sums[0] = 0.0; sums[1] = 0.0; }
}

// f64 row stats + write bf16 A row (xn - pre_bias) in one pass
__global__ __launch_bounds__(256) void k_rowstats(const float* __restrict__ x,
                                                  const float* __restrict__ pre_bias,
                                                  double* __restrict__ muD,
                                                  double* __restrict__ rinvD,
                                                  float* __restrict__ muF,
                                                  float* __restrict__ stdF,
                                                  unsigned short* __restrict__ Ap) {
    const int row = blockIdx.x;
    const int tid = threadIdx.x;
    const float* xr = x + (size_t)row * Dn;
    float v[6];
#pragma unroll
    for (int i = 0; i < 6; ++i) v[i] = xr[tid + 256 * i];
    double s = 0.0;
#pragma unroll
    for (int i = 0; i < 6; ++i) s += (double)v[i];
    __shared__ double redD[4];
    __shared__ double smu, srin;
#pragma unroll
    for (int o = 32; o > 0; o >>= 1) s += __shfl_down(s, o);
    if ((tid & 63) == 0) redD[tid >> 6] = s;
    __syncthreads();
    if (tid == 0) smu = (redD[0] + redD[1] + redD[2] + redD[3]) / (double)Dn;
    __syncthreads();
    const double m = smu;
    double q = 0.0;
#pragma unroll
    for (int i = 0; i < 6; ++i) { double d = (double)v[i] - m; q += d * d; }
#pragma unroll
    for (int o = 32; o > 0; o >>= 1) q += __shfl_down(q, o);
    if ((tid & 63) == 0) redD[tid >> 6] = q;
    __syncthreads();
    if (tid == 0) {
        double var = (redD[0] + redD[1] + redD[2] + redD[3]) / (double)(Dn - 1);
        double sd = sqrt(var);
        muD[row] = m;
        srin = 1.0 / (sd + EPSD);
        rinvD[row] = srin;
        muF[row] = (float)m;
        stdF[row] = (float)sd;
    }
    __syncthreads();
    const double ri = srin;
    unsigned short* ar = Ap + (size_t)row * KE;
#pragma unroll
    for (int i = 0; i < 6; ++i) {
        const int d = tid + i * 256;
        double a = ((double)v[i] - m) * ri - (double)pre_bias[d];
        ar[d] = f2bf((float)a);
    }
}

// Wenc f32 -> bf16
__global__ __launch_bounds__(256) void k_splitW(const float* __restrict__ Wenc,
                                                unsigned short* __restrict__ Bp) {
    const int row = blockIdx.x;
    const int tid = threadIdx.x;
    const float2* wr = (const float2*)(Wenc + (size_t)row * Dn);
    ushort2* br = (ushort2*)(Bp + (size_t)row * KE);
#pragma unroll
    for (int i = 0; i < 3; ++i) {
        float2 w = wr[tid + i * 256];
        ushort2 o; o.x = f2bf(w.x); o.y = f2bf(w.y);
        br[tid + i * 256] = o;
    }
}

// W_dec (D,H) f32 -> W_decT (H,D) bf16 in ws
__global__ __launch_bounds__(256) void k_transpose(const float* __restrict__ Wdec,
                                                   unsigned short* __restrict__ WdecT) {
    __shared__ float tile[32][33];
    const int h0 = blockIdx.x * 32;
    const int d0 = blockIdx.y * 32;
    const int tx = threadIdx.x & 31;
    const int ty = threadIdx.x >> 5;
#pragma unroll
    for (int r = 0; r < 4; ++r) {
        int d = ty + r * 8;
        tile[d][tx] = Wdec[(size_t)(d0 + d) * Hn + h0 + tx];
    }
    __syncthreads();
#pragma unroll
    for (int r = 0; r < 4; ++r) {
        int h = ty + r * 8;
        WdecT[(size_t)(h0 + h) * Dn + d0 + tx] = f2bf(tile[tx][h]);
    }
}

// bf16 MFMA GEMM (round-8 verified core), epilogue writes bf16 h
__global__ __launch_bounds__(256) void k_gemm(const unsigned short* __restrict__ Ap,
                                              const unsigned short* __restrict__ Bp,
                                              const float* __restrict__ lat_bias,
                                              unsigned short* __restrict__ hout16) {
    __shared__ unsigned short As[2][128 * 64];
    __shared__ unsigned short Bs[2][128 * 64];
    const int tid = threadIdx.x;
    const int lane = tid & 63;
    const int w = tid >> 6;
    const int wm = w >> 1, wn = w & 1;

    const int nwg = (Bn / 128) * (Hn / 128);          // 8192
    int swz = (blockIdx.x % 8) * (nwg / 8) + blockIdx.x / 8;
    int st = swz >> 6;
    int wi = swz & 63;
    int stm = st >> 4, stn = st & 15;
    const int bm = stm * 8 + (wi >> 3);
    const int bn = stn * 8 + (wi & 7);

    const int sr = tid >> 3;
    const int sp = tid & 7;
    const int ssl = sp ^ (sr & 7);
    const size_t arow0 = (size_t)(bm * 128) * KE;
    const size_t brow0 = (size_t)(bn * 128) * KE;

    f32x4 acc[4][4];
#pragma unroll
    for (int i = 0; i < 4; ++i)
#pragma unroll
        for (int j = 0; j < 4; ++j) acc[i][j] = (f32x4){0.f, 0.f, 0.f, 0.f};

    constexpr int NT = KE / 64;       // 24
#pragma unroll
    for (int i = 0; i < 4; ++i) {
        gload_lds16(Ap + arow0 + (size_t)(i * 32 + sr) * KE + ssl * 8,
                    (char*)As[0] + i * 4096 + tid * 16);
        gload_lds16(Bp + brow0 + (size_t)(i * 32 + sr) * KE + ssl * 8,
                    (char*)Bs[0] + i * 4096 + tid * 16);
    }
    __syncthreads();

    int cur = 0;
    for (int t = 0; t < NT; ++t) {
        if (t + 1 < NT) {
            const int k1 = (t + 1) * 64;
#pragma unroll
            for (int i = 0; i < 4; ++i) {
                gload_lds16(Ap + arow0 + (size_t)(i * 32 + sr) * KE + k1 + ssl * 8,
                            (char*)As[cur ^ 1] + i * 4096 + tid * 16);
                gload_lds16(Bp + brow0 + (size_t)(i * 32 + sr) * KE + k1 + ssl * 8,
                            (char*)Bs[cur ^ 1] + i * 4096 + tid * 16);
            }
        }
        const unsigned short* Ab = As[cur];
        const unsigned short* Bb = Bs[cur];
#pragma unroll
        for (int kk = 0; kk < 2; ++kk) {
            short8 af[4], bf[4];
#pragma unroll
            for (int f = 0; f < 4; ++f) {
                const int ar = wm * 64 + f * 16 + (lane & 15);
                const int aslot = (kk * 4 + (lane >> 4)) ^ (ar & 7);
                af[f] = *(const short8*)((const char*)Ab + ar * 128 + aslot * 16);
                const int brr = wn * 64 + f * 16 + (lane & 15);
                const int bslot = (kk * 4 + (lane >> 4)) ^ (brr & 7);
                bf[f] = *(const short8*)((const char*)Bb + brr * 128 + bslot * 16);
            }
#pragma unroll
            for (int fi = 0; fi < 4; ++fi)
#pragma unroll
                for (int fj = 0; fj < 4; ++fj)
                    acc[fi][fj] = __builtin_amdgcn_mfma_f32_16x16x32_bf16(
                        af[fi], bf[fj], acc[fi][fj], 0, 0, 0);
        }
        __syncthreads();
        cur ^= 1;
    }

    const int col = lane & 15;
    float biasv[4];
#pragma unroll
    for (int fj = 0; fj < 4; ++fj)
        biasv[fj] = lat_bias[bn * 128 + wn * 64 + fj * 16 + col];
#pragma unroll
    for (int fi = 0; fi < 4; ++fi) {
        const int gm0 = bm * 128 + wm * 64 + fi * 16 + (lane >> 4) * 4;
#pragma unroll
        for (int fj = 0; fj < 4; ++fj) {
            const int gn = bn * 128 + wn * 64 + fj * 16 + col;
#pragma unroll
            for (int r = 0; r < 4; ++r) {
                float vv = acc[fi][fj][r] + biasv[fj];
                hout16[(size_t)(gm0 + r) * Hn + gn] = f2bf(fmaxf(vv, 0.f));
            }
        }
    }
}

// 2-pass 16-bit radix select on bf16 h (parallel suffix-scan bucket select)
__global__ __launch_bounds__(256) void k_thresh(const unsigned short* __restrict__ h16,
                                                float* __restrict__ thr_out) {
    const int row = blockIdx.x;
    const int tid = threadIdx.x;
    const unsigned* hu = (const unsigned*)(h16 + (size_t)row * Hn);
    unsigned u[32];
#pragma unroll
    for (int j = 0; j < 32; ++j) u[j] = hu[j * 256 + tid];

    __shared__ unsigned hist[256];
    __shared__ unsigned sfx[256];
    __shared__ int ssel;
    unsigned remain = KTOP;
    unsigned sel1 = 0;

    // ---- pass 1: high byte ----
    hist[tid] = 0;
    __syncthreads();
#pragma unroll
    for (int j = 0; j < 32; ++j) {
        unsigned k0 = u[j] & 0xFFFFu, k1 = u[j] >> 16;
        if (k0) atomicAdd(&hist[k0 >> 8], 1u);
        if (k1) atomicAdd(&hist[k1 >> 8], 1u);
    }
    __syncthreads();
    sfx[tid] = hist[tid];
    __syncthreads();
#pragma unroll
    for (int o = 1; o < 256; o <<= 1) {
        unsigned t = sfx[tid] + ((tid + o < 256) ? sfx[tid + o] : 0u);
        __syncthreads();
        sfx[tid] = t;
        __syncthreads();
    }
    if (sfx[tid] >= remain && (tid == 255 || sfx[tid + 1] < remain)) ssel = tid;
    __syncthreads();
    sel1 = (unsigned)ssel;
    remain -= (sel1 == 255u) ? 0u : sfx[sel1 + 1];
    __syncthreads();

    // ---- pass 2: low byte within sel1 ----
    hist[tid] = 0;
    __syncthreads();
#pragma unroll
    for (int j = 0; j < 32; ++j) {
        unsigned k0 = u[j] & 0xFFFFu, k1 = u[j] >> 16;
        if (k0 && (k0 >> 8) == sel1) atomicAdd(&hist[k0 & 255u], 1u);
        if (k1 && (k1 >> 8) == sel1) atomicAdd(&hist[k1 & 255u], 1u);
    }
    __syncthreads();
    sfx[tid] = hist[tid];
    __syncthreads();
#pragma unroll
    for (int o = 1; o < 256; o <<= 1) {
        unsigned t = sfx[tid] + ((tid + o < 256) ? sfx[tid + o] : 0u);
        __syncthreads();
        sfx[tid] = t;
        __syncthreads();
    }
    if (sfx[tid] >= remain && (tid == 255 || sfx[tid + 1] < remain)) ssel = tid;
    __syncthreads();
    if (tid == 0)
        thr_out[row] = bf2f((unsigned short)((sel1 << 8) | (unsigned)ssel));
}

// classify + wave-parallel f64 refine + all-wave 3-phase deterministic compaction
__global__ __launch_bounds__(256) void k_select(const unsigned short* __restrict__ h16,
                                                const float* __restrict__ x,
                                                const float* __restrict__ Wenc,
                                                const float* __restrict__ pre_bias,
                                                const float* __restrict__ lat_bias,
                                                const double* __restrict__ muD,
                                                const double* __restrict__ rinvD,
                                                const float* __restrict__ thr_in,
                                                unsigned* __restrict__ counts,
                                                int* __restrict__ idx_list,
                                                float* __restrict__ val_list) {
    const int row = blockIdx.x;
    const int tid = threadIdx.x;
    const int lane = tid & 63;
    const int wid = tid >> 6;
    const unsigned short* hr16 = h16 + (size_t)row * Hn;
    const unsigned* hu = (const unsigned*)hr16;
    const float thr = thr_in[row];
    const float DELTA = 0.02f;        // covers gemm err (<=6e-3) + bf16 rounding (<=8e-3)
    const float hi_t = thr + DELTA;
    const float lo_t = thr - DELTA;

    constexpr int MAXC = 128;
    __shared__ int s_g, s_c;
    __shared__ int cidx[MAXC];
    __shared__ double cvalD[MAXC];
    __shared__ float cref[MAXC];
    __shared__ unsigned char csel[MAXC];
    __shared__ unsigned long long kmask[256];
    __shared__ unsigned ccnt[256];
    __shared__ unsigned cinc[256];
    if (tid == 0) { s_g = 0; s_c = 0; }
    __syncthreads();

    // classify (uint-packed bf16 reads)
    int g_loc = 0;
#pragma unroll
    for (int j = 0; j < 32; ++j) {
        unsigned uu = hu[j * 256 + tid];
        float v0 = bf2f((unsigned short)(uu & 0xFFFFu));
        float v1 = bf2f((unsigned short)(uu >> 16));
        const int i0 = 2 * (j * 256 + tid);
        if (v0 > hi_t) g_loc++;
        else if (v0 >= lo_t) {
            int p = atomicAdd(&s_c, 1);
            if (p < MAXC) cidx[p] = i0;
        }
        if (v1 > hi_t) g_loc++;
        else if (v1 >= lo_t) {
            int p = atomicAdd(&s_c, 1);
            if (p < MAXC) cidx[p] = i0 + 1;
        }
    }
    if (g_loc) atomicAdd(&s_g, g_loc);
    __syncthreads();
    const int ec = (s_c < MAXC) ? s_c : MAXC;

    // exact f64 recompute of band candidates, wave-parallel
    {
        const double rmu = muD[row];
        const double rin = rinvD[row];
        const float* xr = x + (size_t)row * Dn;
        for (int e = wid; e < ec; e += 4) {
            const int feat = cidx[e];
            const float* wr = Wenc + (size_t)feat * Dn;
            double acc = 0.0;
            for (int d = lane; d < Dn; d += 64) {
                double xn = ((double)xr[d] - rmu) * rin - (double)pre_bias[d];
                acc = fma(xn, (double)wr[d], acc);
            }
#pragma unroll
            for (int o = 32; o > 0; o >>= 1) acc += __shfl_down(acc, o);
            if (lane == 0) {
                double hv = acc + (double)lat_bias[feat];
                cvalD[e] = hv;
                float hf = (float)hv;
                cref[e] = hf > 0.f ? hf : 0.f;
            }
        }
    }
    __syncthreads();
    // deterministic top-(64-g) among candidates by (value, lowest index)
    if (tid == 0) {
        const int need = KTOP - s_g;
        for (int e = 0; e < ec; ++e) csel[e] = 0;
        for (int it = 0; it < need && it < ec; ++it) {
            int best = -1; double bv = -1e300; int bidx = 1 << 30;
            for (int e = 0; e < ec; ++e) {
                if (csel[e]) continue;
                if (cvalD[e] > bv || (cvalD[e] == bv && cidx[e] < bidx)) {
                    bv = cvalD[e]; best = e; bidx = cidx[e];
                }
            }
            if (best >= 0) csel[best] = 1;
        }
    }
    __syncthreads();

    // Phase A: per-chunk keep masks (wave w owns chunks [w*64, w*64+64))
    for (int i = 0; i < 64; ++i) {
        const int c = wid * 64 + i;
        const int f = c * 64 + lane;
        float val = bf2f(hr16[f]);
        bool keep;
        if (val > hi_t) keep = true;
        else if (val >= lo_t) {
            keep = false;
            for (int e = 0; e < ec; ++e)
                if (cidx[e] == f) { keep = (csel[e] != 0); break; }
        } else keep = false;
        unsigned long long bm = __ballot(keep);
        if (lane == 0) { kmask[c] = bm; ccnt[c] = (unsigned)__popcll(bm); }
    }
    __syncthreads();
    // Phase B: inclusive prefix over chunk counts
    cinc[tid] = ccnt[tid];
    __syncthreads();
#pragma unroll
    for (int o = 1; o < 256; o <<= 1) {
        unsigned t = cinc[tid] + ((tid >= o) ? cinc[tid - o] : 0u);
        __syncthreads();
        cinc[tid] = t;
        __syncthreads();
    }
    if (tid == 0) {
        unsigned tot = cinc[255];
        counts[row] = tot < 128u ? tot : 128u;
    }
    __syncthreads();
    // Phase C: masked writes
    for (int i = 0; i < 64; ++i) {
        const int c = wid * 64 + i;
        unsigned long long bm = kmask[c];
        if (!bm) continue;
        bool keep = (bm >> lane) & 1ull;
        if (keep) {
            unsigned pos = (cinc[c] - ccnt[c]) +
                           (unsigned)__popcll(bm & ((1ull << lane) - 1ull));
            if (pos < 128u) {
                const int f = c * 64 + lane;
                float sv = bf2f(hr16[f]);
                if (sv >= lo_t && sv <= hi_t) {
                    for (int e = 0; e < ec; ++e)
                        if (cidx[e] == f) { sv = cref[e]; break; }
                }
                idx_list[(size_t)row * 128 + pos] = f;
                val_list[(size_t)row * 128 + pos] = sv;
            }
        }
    }
}

// zero h_sparse region, scatter kept values, accumulate stats (round-6 proven)
__global__ __launch_bounds__(256) void k_hwrite(const unsigned* __restrict__ counts,
                                                const int* __restrict__ idx_list,
                                                const float* __restrict__ val_list,
                                                float* __restrict__ outh,
                                                unsigned* __restrict__ nnz_acc,
                                                double* __restrict__ sums) {
    const int row = blockIdx.x;
    const int tid = threadIdx.x;
    const unsigned cnt = counts[row];
    float* orow = outh + (size_t)row * Hn;
    float4* orow16 = (float4*)orow;
    const float4 z = {0.f, 0.f, 0.f, 0.f};
#pragma unroll
    for (int i = 0; i < 16; ++i) orow16[tid + i * 256] = z;
    __syncthreads();
    float val = 0.f;
    if (tid < (int)cnt) {
        int idx = idx_list[(size_t)row * 128 + tid];
        val = val_list[(size_t)row * 128 + tid];
        orow[idx] = val;
    }
    float s1 = val, s2 = val * val;
    __shared__ float r1[4], r2[4];
#pragma unroll
    for (int o = 32; o > 0; o >>= 1) {
        s1 += __shfl_down(s1, o);
        s2 += __shfl_down(s2, o);
    }
    if ((tid & 63) == 0) { r1[tid >> 6] = s1; r2[tid >> 6] = s2; }
    __syncthreads();
    if (tid == 0) {
        atomicAdd(sums + 0, (double)(r1[0] + r1[1] + r1[2] + r1[3]));
        atomicAdd(sums + 1, (double)(r2[0] + r2[1] + r2[2] + r2[3]));
        atomicAdd(nnz_acc, cnt);
    }
}

// sparse decoder, unroll-2 independent chains (round-7/8 proven)
__global__ __launch_bounds__(256) void k_decoder(const unsigned short* __restrict__ WdecT,
                                                 const float* __restrict__ pre_bias,
                                                 const float* __restrict__ muF,
                                                 const float* __restrict__ stdF,
                                                 const unsigned* __restrict__ counts,
                                                 const int* __restrict__ idx_list,
                                                 const float* __restrict__ val_list,
                                                 float* __restrict__ outr) {
    const int row = blockIdx.x;
    const int tid = threadIdx.x;
    const unsigned cnt = counts[row];
    __shared__ int sidx[128];
    __shared__ float sval[128];
    if (tid < (int)cnt) {
        sidx[tid] = idx_list[(size_t)row * 128 + tid];
        sval[tid] = val_list[(size_t)row * 128 + tid];
    }
    __syncthreads();
    float a0[3] = {0.f, 0.f, 0.f}, a1[3] = {0.f, 0.f, 0.f};
    float b0[3] = {0.f, 0.f, 0.f}, b1[3] = {0.f, 0.f, 0.f};
    unsigned j = 0;
    for (; j + 2 <= cnt; j += 2) {
        const ushort2* w0 = (const ushort2*)(WdecT + (size_t)sidx[j] * Dn);
        const ushort2* w1 = (const ushort2*)(WdecT + (size_t)sidx[j + 1] * Dn);
        const float v0 = sval[j], v1 = sval[j + 1];
#pragma unroll
        for (int i = 0; i < 3; ++i) {
            ushort2 p0 = w0[tid + i * 256];
            ushort2 p1 = w1[tid + i * 256];
            a0[i] = fmaf(v0, bf2f(p0.x), a0[i]);
            a1[i] = fmaf(v0, bf2f(p0.y), a1[i]);
            b0[i] = fmaf(v1, bf2f(p1.x), b0[i]);
            b1[i] = fmaf(v1, bf2f(p1.y), b1[i]);
        }
    }
    if (j < cnt) {
        const ushort2* w0 = (const ushort2*)(WdecT + (size_t)sidx[j] * Dn);
        const float v0 = sval[j];
#pragma unroll
        for (int i = 0; i < 3; ++i) {
            ushort2 p0 = w0[tid + i * 256];
            a0[i] = fmaf(v0, bf2f(p0.x), a0[i]);
            a1[i] = fmaf(v0, bf2f(p0.y), a1[i]);
        }
    }
    const float m_ = muF[row], s_ = stdF[row];
    float2* orow = (float2*)(outr + (size_t)row * Dn);
#pragma unroll
    for (int i = 0; i < 3; ++i) {
        const int p = tid + i * 256;
        float2 o;
        o.x = ((a0[i] + b0[i]) + pre_bias[2 * p + 0]) * s_ + m_;
        o.y = ((a1[i] + b1[i]) + pre_bias[2 * p + 1]) * s_ + m_;
        orow[p] = o;
    }
}

__global__ void k_final(const unsigned* __restrict__ nnz,
                        const double* __restrict__ sums,
                        float* __restrict__ out3) {
    if (threadIdx.x == 0) {
        const double N = (double)Bn * (double)Hn;
        const double nz = (double)(*nnz);
        const double sparsity = (N - nz) / N;
        const double mean = sums[0] / N;
        double var = (sums[1] - N * mean * mean) / (N - 1.0);
        if (var < 0.0) var = 0.0;
        out3[0] = (float)sparsity;
        out3[1] = (float)mean;
        out3[2] = (float)sqrt(var);
    }
}

extern "C" void kernel_launch(void* const* d_in, const int* in_sizes, int n_in,
                              void* d_out, int out_size, void* d_ws, size_t ws_size,
                              hipStream_t stream) {
    const float* x        = (const float*)d_in[0];
    const float* Wenc     = (const float*)d_in[1];
    const float* Wdec     = (const float*)d_in[2];
    const float* pre_bias = (const float*)d_in[3];
    const float* lat_bias = (const float*)d_in[4];

    char* ws = (char*)d_ws;
    float*          muF    = (float*)(ws + MU_OFF);
    float*          stdF   = (float*)(ws + STD_OFF);
    float*          thr    = (float*)(ws + THR_OFF);
    unsigned*       counts = (unsigned*)(ws + CNT_OFF);
    unsigned*       nnz    = (unsigned*)(ws + NNZ_OFF);
    double*         sums   = (double*)(ws + SUM_OFF);
    double*         muD    = (double*)(ws + MUD_OFF);
    double*         rinvD  = (double*)(ws + RID_OFF);
    int*            idxl   = (int*)(ws + IDX_OFF);
    float*          vall   = (float*)(ws + VAL_OFF);
    unsigned short* Ap     = (unsigned short*)(ws + AP_OFF);
    unsigned short* Bp     = (unsigned short*)(ws + BP_OFF);
    unsigned short* WdecT  = (unsigned short*)(ws + WT_OFF);
    unsigned short* h16    = (unsigned short*)(ws + H16_OFF);

    float* out       = (float*)d_out;
    float* out_recon = out;
    float* out_h     = out + (size_t)Bn * Dn;
    float* out_sc    = out + (size_t)Bn * Dn + (size_t)Bn * Hn;

    hipLaunchKernelGGL(k_zero, dim3(1), dim3(64), 0, stream, nnz, sums);
    hipLaunchKernelGGL(k_rowstats, dim3(Bn), dim3(256), 0, stream,
                       x, pre_bias, muD, rinvD, muF, stdF, Ap);
    hipLaunchKernelGGL(k_splitW, dim3(Hn), dim3(256), 0, stream, Wenc, Bp);
    hipLaunchKernelGGL(k_transpose, dim3(Hn / 32, Dn / 32), dim3(256), 0, stream, Wdec, WdecT);
    hipLaunchKernelGGL(k_gemm, dim3((Bn / 128) * (Hn / 128)), dim3(256), 0, stream,
                       Ap, Bp, lat_bias, h16);
    hipLaunchKernelGGL(k_thresh, dim3(Bn), dim3(256), 0, stream, h16, thr);
    hipLaunchKernelGGL(k_select, dim3(Bn), dim3(256), 0, stream,
                       h16, x, Wenc, pre_bias, lat_bias, muD, rinvD, thr,
                       counts, idxl, vall);
    hipLaunchKernelGGL(k_hwrite, dim3(Bn), dim3(256), 0, stream,
                       counts, idxl, vall, out_h, nnz, sums);
    hipLaunchKernelGGL(k_decoder, dim3(Bn), dim3(256), 0, stream,
                       WdecT, pre_bias, muF, stdF, counts, idxl, vall, out_recon);
    hipLaunchKernelGGL(k_final, dim3(1), dim3(64), 0, stream, nnz, sums, out_sc);
}

// Round 10
// 1711.927 us; speedup vs baseline: 3.6699x; 1.0122x over previous
//
#include <hip/hip_runtime.h>
#include <hip/hip_bf16.h>
#include <math.h>

static constexpr int Bn = 8192;
static constexpr int Hn = 16384;
static constexpr int Dn = 1536;
static constexpr int KTOP = 64;
static constexpr int KE = 1536;             // single-pass bf16 GEMM K
static constexpr double EPSD = 1e-5;

// ---- workspace byte offsets (peak ~428 MB; >=672 MB proven mapped, r1/r2) ----
static constexpr size_t MU_OFF  = 0;                 // float[8192]
static constexpr size_t STD_OFF = 32768;             // float[8192]
static constexpr size_t THR_OFF = 65536;             // float[8192]
static constexpr size_t CNT_OFF = 98304;             // unsigned[8192]
static constexpr size_t NNZ_OFF = 131072;            // unsigned[1]
static constexpr size_t SUM_OFF = 131200;            // double[2]
static constexpr size_t MUD_OFF = 262144;            // double[8192]
static constexpr size_t RID_OFF = 327680;            // double[8192]
static constexpr size_t IDX_OFF = (size_t)1 << 20;   // int[8192*128]
static constexpr size_t VAL_OFF = (size_t)6 << 20;   // float[8192*128]
static constexpr size_t AP_OFF  = (size_t)16 << 20;  // bf16[8192*1536]  (25 MB)
static constexpr size_t BP_OFF  = (size_t)48 << 20;  // bf16[16384*1536] (50 MB)
static constexpr size_t WT_OFF  = (size_t)104 << 20; // bf16[16384*1536] (50 MB)
static constexpr size_t H16_OFF = (size_t)160 << 20; // bf16[8192*16384] (268 MB)

typedef __attribute__((ext_vector_type(8))) short short8;
typedef __attribute__((ext_vector_type(4))) float f32x4;

static __device__ __forceinline__ unsigned short f2bf(float f) {
    __hip_bfloat16 b = __float2bfloat16(f);
    return *reinterpret_cast<unsigned short*>(&b);
}
static __device__ __forceinline__ float bf2f(unsigned short u) {
    return __uint_as_float(((unsigned)u) << 16);
}
static __device__ __forceinline__ void gload_lds16(const void* g, void* l) {
    __builtin_amdgcn_global_load_lds(
        (const __attribute__((address_space(1))) unsigned int*)g,
        (__attribute__((address_space(3))) unsigned int*)l, 16, 0, 0);
}

__global__ void k_zero(unsigned* nnz, double* sums) {
    if (threadIdx.x == 0) { *nnz = 0u; sums[0] = 0.0; sums[1] = 0.0; }
}

// f64 row stats + write bf16 A row (xn - pre_bias) in one pass
__global__ __launch_bounds__(256) void k_rowstats(const float* __restrict__ x,
                                                  const float* __restrict__ pre_bias,
                                                  double* __restrict__ muD,
                                                  double* __restrict__ rinvD,
                                                  float* __restrict__ muF,
                                                  float* __restrict__ stdF,
                                                  unsigned short* __restrict__ Ap) {
    const int row = blockIdx.x;
    const int tid = threadIdx.x;
    const float* xr = x + (size_t)row * Dn;
    float v[6];
#pragma unroll
    for (int i = 0; i < 6; ++i) v[i] = xr[tid + 256 * i];
    double s = 0.0;
#pragma unroll
    for (int i = 0; i < 6; ++i) s += (double)v[i];
    __shared__ double redD[4];
    __shared__ double smu, srin;
#pragma unroll
    for (int o = 32; o > 0; o >>= 1) s += __shfl_down(s, o);
    if ((tid & 63) == 0) redD[tid >> 6] = s;
    __syncthreads();
    if (tid == 0) smu = (redD[0] + redD[1] + redD[2] + redD[3]) / (double)Dn;
    __syncthreads();
    const double m = smu;
    double q = 0.0;
#pragma unroll
    for (int i = 0; i < 6; ++i) { double d = (double)v[i] - m; q += d * d; }
#pragma unroll
    for (int o = 32; o > 0; o >>= 1) q += __shfl_down(q, o);
    if ((tid & 63) == 0) redD[tid >> 6] = q;
    __syncthreads();
    if (tid == 0) {
        double var = (redD[0] + redD[1] + redD[2] + redD[3]) / (double)(Dn - 1);
        double sd = sqrt(var);
        muD[row] = m;
        srin = 1.0 / (sd + EPSD);
        rinvD[row] = srin;
        muF[row] = (float)m;
        stdF[row] = (float)sd;
    }
    __syncthreads();
    const double ri = srin;
    unsigned short* ar = Ap + (size_t)row * KE;
#pragma unroll
    for (int i = 0; i < 6; ++i) {
        const int d = tid + i * 256;
        double a = ((double)v[i] - m) * ri - (double)pre_bias[d];
        ar[d] = f2bf((float)a);
    }
}

// Wenc f32 -> bf16
__global__ __launch_bounds__(256) void k_splitW(const float* __restrict__ Wenc,
                                                unsigned short* __restrict__ Bp) {
    const int row = blockIdx.x;
    const int tid = threadIdx.x;
    const float2* wr = (const float2*)(Wenc + (size_t)row * Dn);
    ushort2* br = (ushort2*)(Bp + (size_t)row * KE);
#pragma unroll
    for (int i = 0; i < 3; ++i) {
        float2 w = wr[tid + i * 256];
        ushort2 o; o.x = f2bf(w.x); o.y = f2bf(w.y);
        br[tid + i * 256] = o;
    }
}

// W_dec (D,H) f32 -> W_decT (H,D) bf16 in ws
__global__ __launch_bounds__(256) void k_transpose(const float* __restrict__ Wdec,
                                                   unsigned short* __restrict__ WdecT) {
    __shared__ float tile[32][33];
    const int h0 = blockIdx.x * 32;
    const int d0 = blockIdx.y * 32;
    const int tx = threadIdx.x & 31;
    const int ty = threadIdx.x >> 5;
#pragma unroll
    for (int r = 0; r < 4; ++r) {
        int d = ty + r * 8;
        tile[d][tx] = Wdec[(size_t)(d0 + d) * Hn + h0 + tx];
    }
    __syncthreads();
#pragma unroll
    for (int r = 0; r < 4; ++r) {
        int h = ty + r * 8;
        WdecT[(size_t)(h0 + h) * Dn + d0 + tx] = f2bf(tile[tx][h]);
    }
}

// bf16 MFMA GEMM, single-buffer m97 structure (32 KB LDS -> higher occupancy),
// XOR bank-swizzle kept (round-6: conflicts 4.5e8 -> 0). Writes bf16 h.
__global__ __launch_bounds__(256) void k_gemm(const unsigned short* __restrict__ Ap,
                                              const unsigned short* __restrict__ Bp,
                                              const float* __restrict__ lat_bias,
                                              unsigned short* __restrict__ hout16) {
    __shared__ unsigned short As[128 * 64];   // 16 KB
    __shared__ unsigned short Bs[128 * 64];   // 16 KB
    const int tid = threadIdx.x;
    const int lane = tid & 63;
    const int w = tid >> 6;
    const int wm = w >> 1, wn = w & 1;

    const int nwg = (Bn / 128) * (Hn / 128);          // 8192
    int swz = (blockIdx.x % 8) * (nwg / 8) + blockIdx.x / 8;
    int st = swz >> 6;
    int wi = swz & 63;
    int stm = st >> 4, stn = st & 15;
    const int bm = stm * 8 + (wi >> 3);
    const int bn = stn * 8 + (wi & 7);

    const int sr = tid >> 3;
    const int sp = tid & 7;
    const int ssl = sp ^ (sr & 7);
    const size_t arow0 = (size_t)(bm * 128) * KE;
    const size_t brow0 = (size_t)(bn * 128) * KE;

    f32x4 acc[4][4];
#pragma unroll
    for (int i = 0; i < 4; ++i)
#pragma unroll
        for (int j = 0; j < 4; ++j) acc[i][j] = (f32x4){0.f, 0.f, 0.f, 0.f};

    constexpr int NT = KE / 64;       // 24
    for (int t = 0; t < NT; ++t) {
        const int k0 = t * 64;
#pragma unroll
        for (int i = 0; i < 4; ++i) {
            gload_lds16(Ap + arow0 + (size_t)(i * 32 + sr) * KE + k0 + ssl * 8,
                        (char*)As + i * 4096 + tid * 16);
            gload_lds16(Bp + brow0 + (size_t)(i * 32 + sr) * KE + k0 + ssl * 8,
                        (char*)Bs + i * 4096 + tid * 16);
        }
        __syncthreads();
#pragma unroll
        for (int kk = 0; kk < 2; ++kk) {
            short8 af[4], bf[4];
#pragma unroll
            for (int f = 0; f < 4; ++f) {
                const int ar = wm * 64 + f * 16 + (lane & 15);
                const int aslot = (kk * 4 + (lane >> 4)) ^ (ar & 7);
                af[f] = *(const short8*)((const char*)As + ar * 128 + aslot * 16);
                const int brr = wn * 64 + f * 16 + (lane & 15);
                const int bslot = (kk * 4 + (lane >> 4)) ^ (brr & 7);
                bf[f] = *(const short8*)((const char*)Bs + brr * 128 + bslot * 16);
            }
#pragma unroll
            for (int fi = 0; fi < 4; ++fi)
#pragma unroll
                for (int fj = 0; fj < 4; ++fj)
                    acc[fi][fj] = __builtin_amdgcn_mfma_f32_16x16x32_bf16(
                        af[fi], bf[fj], acc[fi][fj], 0, 0, 0);
        }
        __syncthreads();   // protect LDS from next iteration's staging
    }

    const int col = lane & 15;
    float biasv[4];
#pragma unroll
    for (int fj = 0; fj < 4; ++fj)
        biasv[fj] = lat_bias[bn * 128 + wn * 64 + fj * 16 + col];
#pragma unroll
    for (int fi = 0; fi < 4; ++fi) {
        const int gm0 = bm * 128 + wm * 64 + fi * 16 + (lane >> 4) * 4;
#pragma unroll
        for (int fj = 0; fj < 4; ++fj) {
            const int gn = bn * 128 + wn * 64 + fj * 16 + col;
#pragma unroll
            for (int r = 0; r < 4; ++r) {
                float vv = acc[fi][fj][r] + biasv[fj];
                hout16[(size_t)(gm0 + r) * Hn + gn] = f2bf(fmaxf(vv, 0.f));
            }
        }
    }
}

// exact 64th-largest bf16 key via atomic-free 16-bit bisection.
// largest t with count(v >= t) >= KTOP is exactly v_(KTOP) (unsigned-ordered
// nonneg bf16 keys). Identical result to the radix select, zero LDS atomics.
__global__ __launch_bounds__(256) void k_thresh(const unsigned short* __restrict__ h16,
                                                float* __restrict__ thr_out) {
    const int row = blockIdx.x;
    const int tid = threadIdx.x;
    const unsigned* hu = (const unsigned*)(h16 + (size_t)row * Hn);
    unsigned u[32];
#pragma unroll
    for (int j = 0; j < 32; ++j) u[j] = hu[j * 256 + tid];

    __shared__ int wsum[4];
    __shared__ unsigned sbc;
    unsigned lo = 0, hi = 0xFFFFu;
    while (lo < hi) {                       // 16 iterations
        const unsigned mid = (lo + hi + 1) >> 1;
        int c = 0;
#pragma unroll
        for (int j = 0; j < 32; ++j) {
            c += ((u[j] & 0xFFFFu) >= mid) ? 1 : 0;
            c += ((u[j] >> 16) >= mid) ? 1 : 0;
        }
#pragma unroll
        for (int o = 32; o > 0; o >>= 1) c += __shfl_down(c, o);
        if ((tid & 63) == 0) wsum[tid >> 6] = c;
        __syncthreads();
        if (tid == 0) sbc = (unsigned)(wsum[0] + wsum[1] + wsum[2] + wsum[3]);
        __syncthreads();
        if (sbc >= (unsigned)KTOP) lo = mid; else hi = mid - 1;
    }
    if (tid == 0) thr_out[row] = bf2f((unsigned short)lo);
}

// classify + wave-parallel f64 refine + all-wave 3-phase deterministic compaction
__global__ __launch_bounds__(256) void k_select(const unsigned short* __restrict__ h16,
                                                const float* __restrict__ x,
                                                const float* __restrict__ Wenc,
                                                const float* __restrict__ pre_bias,
                                                const float* __restrict__ lat_bias,
                                                const double* __restrict__ muD,
                                                const double* __restrict__ rinvD,
                                                const float* __restrict__ thr_in,
                                                unsigned* __restrict__ counts,
                                                int* __restrict__ idx_list,
                                                float* __restrict__ val_list) {
    const int row = blockIdx.x;
    const int tid = threadIdx.x;
    const int lane = tid & 63;
    const int wid = tid >> 6;
    const unsigned short* hr16 = h16 + (size_t)row * Hn;
    const unsigned* hu = (const unsigned*)hr16;
    const float thr = thr_in[row];
    const float DELTA = 0.02f;        // covers gemm err (<=6e-3) + bf16 rounding (<=8e-3)
    const float hi_t = thr + DELTA;
    const float lo_t = thr - DELTA;

    constexpr int MAXC = 128;
    __shared__ int s_g, s_c;
    __shared__ int cidx[MAXC];
    __shared__ double cvalD[MAXC];
    __shared__ float cref[MAXC];
    __shared__ unsigned char csel[MAXC];
    __shared__ unsigned long long kmask[256];
    __shared__ unsigned ccnt[256];
    __shared__ unsigned cinc[256];
    if (tid == 0) { s_g = 0; s_c = 0; }
    __syncthreads();

    int g_loc = 0;
#pragma unroll
    for (int j = 0; j < 32; ++j) {
        unsigned uu = hu[j * 256 + tid];
        float v0 = bf2f((unsigned short)(uu & 0xFFFFu));
        float v1 = bf2f((unsigned short)(uu >> 16));
        const int i0 = 2 * (j * 256 + tid);
        if (v0 > hi_t) g_loc++;
        else if (v0 >= lo_t) {
            int p = atomicAdd(&s_c, 1);
            if (p < MAXC) cidx[p] = i0;
        }
        if (v1 > hi_t) g_loc++;
        else if (v1 >= lo_t) {
            int p = atomicAdd(&s_c, 1);
            if (p < MAXC) cidx[p] = i0 + 1;
        }
    }
    if (g_loc) atomicAdd(&s_g, g_loc);
    __syncthreads();
    const int ec = (s_c < MAXC) ? s_c : MAXC;

    // exact f64 recompute of band candidates, wave-parallel
    {
        const double rmu = muD[row];
        const double rin = rinvD[row];
        const float* xr = x + (size_t)row * Dn;
        for (int e = wid; e < ec; e += 4) {
            const int feat = cidx[e];
            const float* wr = Wenc + (size_t)feat * Dn;
            double acc = 0.0;
            for (int d = lane; d < Dn; d += 64) {
                double xn = ((double)xr[d] - rmu) * rin - (double)pre_bias[d];
                acc = fma(xn, (double)wr[d], acc);
            }
#pragma unroll
            for (int o = 32; o > 0; o >>= 1) acc += __shfl_down(acc, o);
            if (lane == 0) {
                double hv = acc + (double)lat_bias[feat];
                cvalD[e] = hv;
                float hf = (float)hv;
                cref[e] = hf > 0.f ? hf : 0.f;
            }
        }
    }
    __syncthreads();
    if (tid == 0) {
        const int need = KTOP - s_g;
        for (int e = 0; e < ec; ++e) csel[e] = 0;
        for (int it = 0; it < need && it < ec; ++it) {
            int best = -1; double bv = -1e300; int bidx = 1 << 30;
            for (int e = 0; e < ec; ++e) {
                if (csel[e]) continue;
                if (cvalD[e] > bv || (cvalD[e] == bv && cidx[e] < bidx)) {
                    bv = cvalD[e]; best = e; bidx = cidx[e];
                }
            }
            if (best >= 0) csel[best] = 1;
        }
    }
    __syncthreads();

    // Phase A: per-chunk keep masks
    for (int i = 0; i < 64; ++i) {
        const int c = wid * 64 + i;
        const int f = c * 64 + lane;
        float val = bf2f(hr16[f]);
        bool keep;
        if (val > hi_t) keep = true;
        else if (val >= lo_t) {
            keep = false;
            for (int e = 0; e < ec; ++e)
                if (cidx[e] == f) { keep = (csel[e] != 0); break; }
        } else keep = false;
        unsigned long long bm = __ballot(keep);
        if (lane == 0) { kmask[c] = bm; ccnt[c] = (unsigned)__popcll(bm); }
    }
    __syncthreads();
    // Phase B: inclusive prefix over chunk counts
    cinc[tid] = ccnt[tid];
    __syncthreads();
#pragma unroll
    for (int o = 1; o < 256; o <<= 1) {
        unsigned t = cinc[tid] + ((tid >= o) ? cinc[tid - o] : 0u);
        __syncthreads();
        cinc[tid] = t;
        __syncthreads();
    }
    if (tid == 0) {
        unsigned tot = cinc[255];
        counts[row] = tot < 128u ? tot : 128u;
    }
    __syncthreads();
    // Phase C: masked writes
    for (int i = 0; i < 64; ++i) {
        const int c = wid * 64 + i;
        unsigned long long bm = kmask[c];
        if (!bm) continue;
        bool keep = (bm >> lane) & 1ull;
        if (keep) {
            unsigned pos = (cinc[c] - ccnt[c]) +
                           (unsigned)__popcll(bm & ((1ull << lane) - 1ull));
            if (pos < 128u) {
                const int f = c * 64 + lane;
                float sv = bf2f(hr16[f]);
                if (sv >= lo_t && sv <= hi_t) {
                    for (int e = 0; e < ec; ++e)
                        if (cidx[e] == f) { sv = cref[e]; break; }
                }
                idx_list[(size_t)row * 128 + pos] = f;
                val_list[(size_t)row * 128 + pos] = sv;
            }
        }
    }
}

// zero h_sparse region, scatter kept values, accumulate stats (round-6 proven)
__global__ __launch_bounds__(256) void k_hwrite(const unsigned* __restrict__ counts,
                                                const int* __restrict__ idx_list,
                                                const float* __restrict__ val_list,
                                                float* __restrict__ outh,
                                                unsigned* __restrict__ nnz_acc,
                                                double* __restrict__ sums) {
    const int row = blockIdx.x;
    const int tid = threadIdx.x;
    const unsigned cnt = counts[row];
    float* orow = outh + (size_t)row * Hn;
    float4* orow16 = (float4*)orow;
    const float4 z = {0.f, 0.f, 0.f, 0.f};
#pragma unroll
    for (int i = 0; i < 16; ++i) orow16[tid + i * 256] = z;
    __syncthreads();
    float val = 0.f;
    if (tid < (int)cnt) {
        int idx = idx_list[(size_t)row * 128 + tid];
        val = val_list[(size_t)row * 128 + tid];
        orow[idx] = val;
    }
    float s1 = val, s2 = val * val;
    __shared__ float r1[4], r2[4];
#pragma unroll
    for (int o = 32; o > 0; o >>= 1) {
        s1 += __shfl_down(s1, o);
        s2 += __shfl_down(s2, o);
    }
    if ((tid & 63) == 0) { r1[tid >> 6] = s1; r2[tid >> 6] = s2; }
    __syncthreads();
    if (tid == 0) {
        atomicAdd(sums + 0, (double)(r1[0] + r1[1] + r1[2] + r1[3]));
        atomicAdd(sums + 1, (double)(r2[0] + r2[1] + r2[2] + r2[3]));
        atomicAdd(nnz_acc, cnt);
    }
}

// sparse decoder, unroll-2 independent chains (round-7/8 proven)
__global__ __launch_bounds__(256) void k_decoder(const unsigned short* __restrict__ WdecT,
                                                 const float* __restrict__ pre_bias,
                                                 const float* __restrict__ muF,
                                                 const float* __restrict__ stdF,
                                                 const unsigned* __restrict__ counts,
                                                 const int* __restrict__ idx_list,
                                                 const float* __restrict__ val_list,
                                                 float* __restrict__ outr) {
    const int row = blockIdx.x;
    const int tid = threadIdx.x;
    const unsigned cnt = counts[row];
    __shared__ int sidx[128];
    __shared__ float sval[128];
    if (tid < (int)cnt) {
        sidx[tid] = idx_list[(size_t)row * 128 + tid];
        sval[tid] = val_list[(size_t)row * 128 + tid];
    }
    __syncthreads();
    float a0[3] = {0.f, 0.f, 0.f}, a1[3] = {0.f, 0.f, 0.f};
    float b0[3] = {0.f, 0.f, 0.f}, b1[3] = {0.f, 0.f, 0.f};
    unsigned j = 0;
    for (; j + 2 <= cnt; j += 2) {
        const ushort2* w0 = (const ushort2*)(WdecT + (size_t)sidx[j] * Dn);
        const ushort2* w1 = (const ushort2*)(WdecT + (size_t)sidx[j + 1] * Dn);
        const float v0 = sval[j], v1 = sval[j + 1];
#pragma unroll
        for (int i = 0; i < 3; ++i) {
            ushort2 p0 = w0[tid + i * 256];
            ushort2 p1 = w1[tid + i * 256];
            a0[i] = fmaf(v0, bf2f(p0.x), a0[i]);
            a1[i] = fmaf(v0, bf2f(p0.y), a1[i]);
            b0[i] = fmaf(v1, bf2f(p1.x), b0[i]);
            b1[i] = fmaf(v1, bf2f(p1.y), b1[i]);
        }
    }
    if (j < cnt) {
        const ushort2* w0 = (const ushort2*)(WdecT + (size_t)sidx[j] * Dn);
        const float v0 = sval[j];
#pragma unroll
        for (int i = 0; i < 3; ++i) {
            ushort2 p0 = w0[tid + i * 256];
            a0[i] = fmaf(v0, bf2f(p0.x), a0[i]);
            a1[i] = fmaf(v0, bf2f(p0.y), a1[i]);
        }
    }
    const float m_ = muF[row], s_ = stdF[row];
    float2* orow = (float2*)(outr + (size_t)row * Dn);
#pragma unroll
    for (int i = 0; i < 3; ++i) {
        const int p = tid + i * 256;
        float2 o;
        o.x = ((a0[i] + b0[i]) + pre_bias[2 * p + 0]) * s_ + m_;
        o.y = ((a1[i] + b1[i]) + pre_bias[2 * p + 1]) * s_ + m_;
        orow[p] = o;
    }
}

__global__ void k_final(const unsigned* __restrict__ nnz,
                        const double* __restrict__ sums,
                        float* __restrict__ out3) {
    if (threadIdx.x == 0) {
        const double N = (double)Bn * (double)Hn;
        const double nz = (double)(*nnz);
        const double sparsity = (N - nz) / N;
        const double mean = sums[0] / N;
        double var = (sums[1] - N * mean * mean) / (N - 1.0);
        if (var < 0.0) var = 0.0;
        out3[0] = (float)sparsity;
        out3[1] = (float)mean;
        out3[2] = (float)sqrt(var);
    }
}

extern "C" void kernel_launch(void* const* d_in, const int* in_sizes, int n_in,
                              void* d_out, int out_size, void* d_ws, size_t ws_size,
                              hipStream_t stream) {
    const float* x        = (const float*)d_in[0];
    const float* Wenc     = (const float*)d_in[1];
    const float* Wdec     = (const float*)d_in[2];
    const float* pre_bias = (const float*)d_in[3];
    const float* lat_bias = (const float*)d_in[4];

    char* ws = (char*)d_ws;
    float*          muF    = (float*)(ws + MU_OFF);
    float*          stdF   = (float*)(ws + STD_OFF);
    float*          thr    = (float*)(ws + THR_OFF);
    unsigned*       counts = (unsigned*)(ws + CNT_OFF);
    unsigned*       nnz    = (unsigned*)(ws + NNZ_OFF);
    double*         sums   = (double*)(ws + SUM_OFF);
    double*         muD    = (double*)(ws + MUD_OFF);
    double*         rinvD  = (double*)(ws + RID_OFF);
    int*            idxl   = (int*)(ws + IDX_OFF);
    float*          vall   = (float*)(ws + VAL_OFF);
    unsigned short* Ap     = (unsigned short*)(ws + AP_OFF);
    unsigned short* Bp     = (unsigned short*)(ws + BP_OFF);
    unsigned short* WdecT  = (unsigned short*)(ws + WT_OFF);
    unsigned short* h16    = (unsigned short*)(ws + H16_OFF);

    float* out       = (float*)d_out;
    float* out_recon = out;
    float* out_h     = out + (size_t)Bn * Dn;
    float* out_sc    = out + (size_t)Bn * Dn + (size_t)Bn * Hn;

    hipLaunchKernelGGL(k_zero, dim3(1), dim3(64), 0, stream, nnz, sums);
    hipLaunchKernelGGL(k_rowstats, dim3(Bn), dim3(256), 0, stream,
                       x, pre_bias, muD, rinvD, muF, stdF, Ap);
    hipLaunchKernelGGL(k_splitW, dim3(Hn), dim3(256), 0, stream, Wenc, Bp);
    hipLaunchKernelGGL(k_transpose, dim3(Hn / 32, Dn / 32), dim3(256), 0, stream, Wdec, WdecT);
    hipLaunchKernelGGL(k_gemm, dim3((Bn / 128) * (Hn / 128)), dim3(256), 0, stream,
                       Ap, Bp, lat_bias, h16);
    hipLaunchKernelGGL(k_thresh, dim3(Bn), dim3(256), 0, stream, h16, thr);
    hipLaunchKernelGGL(k_select, dim3(Bn), dim3(256), 0, stream,
                       h16, x, Wenc, pre_bias, lat_bias, muD, rinvD, thr,
                       counts, idxl, vall);
    hipLaunchKernelGGL(k_hwrite, dim3(Bn), dim3(256), 0, stream,
                       counts, idxl, vall, out_h, nnz, sums);
    hipLaunchKernelGGL(k_decoder, dim3(Bn), dim3(256), 0, stream,
                       WdecT, pre_bias, muF, stdF, counts, idxl, vall, out_recon);
    hipLaunchKernelGGL(k_final, dim3(1), dim3(64), 0, stream, nnz, sums, out_sc);
}

// Round 11
// 1602.050 us; speedup vs baseline: 3.9216x; 1.0686x over previous
//
#include <hip/hip_runtime.h>
#include <hip/hip_bf16.h>
#include <math.h>

static constexpr int Bn = 8192;
static constexpr int Hn = 16384;
static constexpr int Dn = 1536;
static constexpr int KTOP = 64;
static constexpr int KE = 1536;             // single-pass bf16 GEMM K
static constexpr int WSTR = 2048;           // padded W_decT row stride (bf16)
static constexpr double EPSD = 1e-5;

// ---- workspace byte offsets (peak ~444 MB; >=672 MB proven mapped, r1/r2) ----
static constexpr size_t MU_OFF  = 0;                 // float[8192]
static constexpr size_t STD_OFF = 32768;             // float[8192]
static constexpr size_t CNT_OFF = 98304;             // unsigned[8192]
static constexpr size_t NNZ_OFF = 131072;            // unsigned[1]
static constexpr size_t SUM_OFF = 131200;            // double[2]
static constexpr size_t MUD_OFF = 262144;            // double[8192]
static constexpr size_t RID_OFF = 327680;            // double[8192]
static constexpr size_t IDX_OFF = (size_t)1 << 20;   // int[8192*128]
static constexpr size_t VAL_OFF = (size_t)6 << 20;   // float[8192*128]
static constexpr size_t AP_OFF  = (size_t)16 << 20;  // bf16[8192*1536]   (25 MB)
static constexpr size_t BP_OFF  = (size_t)48 << 20;  // bf16[16384*1536]  (50 MB)
static constexpr size_t WT_OFF  = (size_t)104 << 20; // bf16[16384*2048]  (64 MB)
static constexpr size_t H16_OFF = (size_t)176 << 20; // bf16[8192*16384] (268 MB)

typedef __attribute__((ext_vector_type(8))) short short8;
typedef __attribute__((ext_vector_type(4))) float f32x4;

static __device__ __forceinline__ unsigned short f2bf(float f) {
    __hip_bfloat16 b = __float2bfloat16(f);
    return *reinterpret_cast<unsigned short*>(&b);
}
static __device__ __forceinline__ float bf2f(unsigned short u) {
    return __uint_as_float(((unsigned)u) << 16);
}
static __device__ __forceinline__ void gload_lds16(const void* g, void* l) {
    __builtin_amdgcn_global_load_lds(
        (const __attribute__((address_space(1))) unsigned int*)g,
        (__attribute__((address_space(3))) unsigned int*)l, 16, 0, 0);
}

__global__ void k_zero(unsigned* nnz, double* sums) {
    if (threadIdx.x == 0) { *nnz = 0u; sums[0] = 0.0; sums[1] = 0.0; }
}

// f64 row stats + write bf16 A row (xn - pre_bias) in one pass
__global__ __launch_bounds__(256) void k_rowstats(const float* __restrict__ x,
                                                  const float* __restrict__ pre_bias,
                                                  double* __restrict__ muD,
                                                  double* __restrict__ rinvD,
                                                  float* __restrict__ muF,
                                                  float* __restrict__ stdF,
                                                  unsigned short* __restrict__ Ap) {
    const int row = blockIdx.x;
    const int tid = threadIdx.x;
    const float* xr = x + (size_t)row * Dn;
    float v[6];
#pragma unroll
    for (int i = 0; i < 6; ++i) v[i] = xr[tid + 256 * i];
    double s = 0.0;
#pragma unroll
    for (int i = 0; i < 6; ++i) s += (double)v[i];
    __shared__ double redD[4];
    __shared__ double smu, srin;
#pragma unroll
    for (int o = 32; o > 0; o >>= 1) s += __shfl_down(s, o);
    if ((tid & 63) == 0) redD[tid >> 6] = s;
    __syncthreads();
    if (tid == 0) smu = (redD[0] + redD[1] + redD[2] + redD[3]) / (double)Dn;
    __syncthreads();
    const double m = smu;
    double q = 0.0;
#pragma unroll
    for (int i = 0; i < 6; ++i) { double d = (double)v[i] - m; q += d * d; }
#pragma unroll
    for (int o = 32; o > 0; o >>= 1) q += __shfl_down(q, o);
    if ((tid & 63) == 0) redD[tid >> 6] = q;
    __syncthreads();
    if (tid == 0) {
        double var = (redD[0] + redD[1] + redD[2] + redD[3]) / (double)(Dn - 1);
        double sd = sqrt(var);
        muD[row] = m;
        srin = 1.0 / (sd + EPSD);
        rinvD[row] = srin;
        muF[row] = (float)m;
        stdF[row] = (float)sd;
    }
    __syncthreads();
    const double ri = srin;
    unsigned short* ar = Ap + (size_t)row * KE;
#pragma unroll
    for (int i = 0; i < 6; ++i) {
        const int d = tid + i * 256;
        double a = ((double)v[i] - m) * ri - (double)pre_bias[d];
        ar[d] = f2bf((float)a);
    }
}

// Wenc f32 -> bf16
__global__ __launch_bounds__(256) void k_splitW(const float* __restrict__ Wenc,
                                                unsigned short* __restrict__ Bp) {
    const int row = blockIdx.x;
    const int tid = threadIdx.x;
    const float2* wr = (const float2*)(Wenc + (size_t)row * Dn);
    ushort2* br = (ushort2*)(Bp + (size_t)row * KE);
#pragma unroll
    for (int i = 0; i < 3; ++i) {
        float2 w = wr[tid + i * 256];
        ushort2 o; o.x = f2bf(w.x); o.y = f2bf(w.y);
        br[tid + i * 256] = o;
    }
}

// W_dec (D,H) f32 -> W_decT (H, stride WSTR) bf16 in ws; pads never read
__global__ __launch_bounds__(256) void k_transpose(const float* __restrict__ Wdec,
                                                   unsigned short* __restrict__ WdecT) {
    __shared__ float tile[32][33];
    const int h0 = blockIdx.x * 32;
    const int d0 = blockIdx.y * 32;
    const int tx = threadIdx.x & 31;
    const int ty = threadIdx.x >> 5;
#pragma unroll
    for (int r = 0; r < 4; ++r) {
        int d = ty + r * 8;
        tile[d][tx] = Wdec[(size_t)(d0 + d) * Hn + h0 + tx];
    }
    __syncthreads();
#pragma unroll
    for (int r = 0; r < 4; ++r) {
        int h = ty + r * 8;
        WdecT[(size_t)(h0 + h) * WSTR + d0 + tx] = f2bf(tile[tx][h]);
    }
}

// bf16 MFMA GEMM, single-buffer m97 structure + XOR bank-swizzle (r6/r10 verified)
__global__ __launch_bounds__(256) void k_gemm(const unsigned short* __restrict__ Ap,
                                              const unsigned short* __restrict__ Bp,
                                              const float* __restrict__ lat_bias,
                                              unsigned short* __restrict__ hout16) {
    __shared__ unsigned short As[128 * 64];   // 16 KB
    __shared__ unsigned short Bs[128 * 64];   // 16 KB
    const int tid = threadIdx.x;
    const int lane = tid & 63;
    const int w = tid >> 6;
    const int wm = w >> 1, wn = w & 1;

    const int nwg = (Bn / 128) * (Hn / 128);          // 8192
    int swz = (blockIdx.x % 8) * (nwg / 8) + blockIdx.x / 8;
    int st = swz >> 6;
    int wi = swz & 63;
    int stm = st >> 4, stn = st & 15;
    const int bm = stm * 8 + (wi >> 3);
    const int bn = stn * 8 + (wi & 7);

    const int sr = tid >> 3;
    const int sp = tid & 7;
    const int ssl = sp ^ (sr & 7);
    const size_t arow0 = (size_t)(bm * 128) * KE;
    const size_t brow0 = (size_t)(bn * 128) * KE;

    f32x4 acc[4][4];
#pragma unroll
    for (int i = 0; i < 4; ++i)
#pragma unroll
        for (int j = 0; j < 4; ++j) acc[i][j] = (f32x4){0.f, 0.f, 0.f, 0.f};

    constexpr int NT = KE / 64;       // 24
    for (int t = 0; t < NT; ++t) {
        const int k0 = t * 64;
#pragma unroll
        for (int i = 0; i < 4; ++i) {
            gload_lds16(Ap + arow0 + (size_t)(i * 32 + sr) * KE + k0 + ssl * 8,
                        (char*)As + i * 4096 + tid * 16);
            gload_lds16(Bp + brow0 + (size_t)(i * 32 + sr) * KE + k0 + ssl * 8,
                        (char*)Bs + i * 4096 + tid * 16);
        }
        __syncthreads();
#pragma unroll
        for (int kk = 0; kk < 2; ++kk) {
            short8 af[4], bf[4];
#pragma unroll
            for (int f = 0; f < 4; ++f) {
                const int ar = wm * 64 + f * 16 + (lane & 15);
                const int aslot = (kk * 4 + (lane >> 4)) ^ (ar & 7);
                af[f] = *(const short8*)((const char*)As + ar * 128 + aslot * 16);
                const int brr = wn * 64 + f * 16 + (lane & 15);
                const int bslot = (kk * 4 + (lane >> 4)) ^ (brr & 7);
                bf[f] = *(const short8*)((const char*)Bs + brr * 128 + bslot * 16);
            }
#pragma unroll
            for (int fi = 0; fi < 4; ++fi)
#pragma unroll
                for (int fj = 0; fj < 4; ++fj)
                    acc[fi][fj] = __builtin_amdgcn_mfma_f32_16x16x32_bf16(
                        af[fi], bf[fj], acc[fi][fj], 0, 0, 0);
        }
        __syncthreads();
    }

    const int col = lane & 15;
    float biasv[4];
#pragma unroll
    for (int fj = 0; fj < 4; ++fj)
        biasv[fj] = lat_bias[bn * 128 + wn * 64 + fj * 16 + col];
#pragma unroll
    for (int fi = 0; fi < 4; ++fi) {
        const int gm0 = bm * 128 + wm * 64 + fi * 16 + (lane >> 4) * 4;
#pragma unroll
        for (int fj = 0; fj < 4; ++fj) {
            const int gn = bn * 128 + wn * 64 + fj * 16 + col;
#pragma unroll
            for (int r = 0; r < 4; ++r) {
                float vv = acc[fi][fj][r] + biasv[fj];
                hout16[(size_t)(gm0 + r) * Hn + gn] = f2bf(fmaxf(vv, 0.f));
            }
        }
    }
}

// FUSED: bisect threshold (registers) + classify (registers) + f64 band refine
// + deterministic selection + 3-phase compaction. One h16 HBM sweep total.
__global__ __launch_bounds__(256) void k_topsel(const unsigned short* __restrict__ h16,
                                                const float* __restrict__ x,
                                                const float* __restrict__ Wenc,
                                                const float* __restrict__ pre_bias,
                                                const float* __restrict__ lat_bias,
                                                const double* __restrict__ muD,
                                                const double* __restrict__ rinvD,
                                                unsigned* __restrict__ counts,
                                                int* __restrict__ idx_list,
                                                float* __restrict__ val_list) {
    const int row = blockIdx.x;
    const int tid = threadIdx.x;
    const int lane = tid & 63;
    const int wid = tid >> 6;
    const unsigned short* hr16 = h16 + (size_t)row * Hn;
    const unsigned* hu = (const unsigned*)hr16;
    unsigned u[32];
#pragma unroll
    for (int j = 0; j < 32; ++j) u[j] = hu[j * 256 + tid];

    // ---- exact 64th-largest bf16 key via atomic-free bisection (r10 verified)
    __shared__ int wsum[4];
    __shared__ unsigned sbc;
    unsigned lo = 0, hi = 0xFFFFu;
    while (lo < hi) {
        const unsigned mid = (lo + hi + 1) >> 1;
        int c = 0;
#pragma unroll
        for (int j = 0; j < 32; ++j) {
            c += ((u[j] & 0xFFFFu) >= mid) ? 1 : 0;
            c += ((u[j] >> 16) >= mid) ? 1 : 0;
        }
#pragma unroll
        for (int o = 32; o > 0; o >>= 1) c += __shfl_down(c, o);
        if ((tid & 63) == 0) wsum[tid >> 6] = c;
        __syncthreads();
        if (tid == 0) sbc = (unsigned)(wsum[0] + wsum[1] + wsum[2] + wsum[3]);
        __syncthreads();
        if (sbc >= (unsigned)KTOP) lo = mid; else hi = mid - 1;
    }
    const float thr = bf2f((unsigned short)lo);
    const float DELTA = 0.02f;        // covers gemm err (<=6e-3) + bf16 rounding (<=8e-3)
    const float hi_t = thr + DELTA;
    const float lo_t = thr - DELTA;

    // ---- classify from registers (no h16 re-read)
    constexpr int MAXC = 128;
    __shared__ int s_g, s_c;
    __shared__ int cidx[MAXC];
    __shared__ double cvalD[MAXC];
    __shared__ float cref[MAXC];
    __shared__ unsigned char csel[MAXC];
    __shared__ unsigned long long kmask[256];
    __shared__ unsigned ccnt[256];
    __shared__ unsigned cinc[256];
    if (tid == 0) { s_g = 0; s_c = 0; }
    __syncthreads();
    int g_loc = 0;
#pragma unroll
    for (int j = 0; j < 32; ++j) {
        float v0 = bf2f((unsigned short)(u[j] & 0xFFFFu));
        float v1 = bf2f((unsigned short)(u[j] >> 16));
        const int i0 = 2 * (j * 256 + tid);
        if (v0 > hi_t) g_loc++;
        else if (v0 >= lo_t) {
            int p = atomicAdd(&s_c, 1);
            if (p < MAXC) cidx[p] = i0;
        }
        if (v1 > hi_t) g_loc++;
        else if (v1 >= lo_t) {
            int p = atomicAdd(&s_c, 1);
            if (p < MAXC) cidx[p] = i0 + 1;
        }
    }
    if (g_loc) atomicAdd(&s_g, g_loc);
    __syncthreads();
    const int ec = (s_c < MAXC) ? s_c : MAXC;

    // ---- exact f64 recompute of band candidates, wave-parallel
    {
        const double rmu = muD[row];
        const double rin = rinvD[row];
        const float* xr = x + (size_t)row * Dn;
        for (int e = wid; e < ec; e += 4) {
            const int feat = cidx[e];
            const float* wr = Wenc + (size_t)feat * Dn;
            double acc = 0.0;
            for (int d = lane; d < Dn; d += 64) {
                double xn = ((double)xr[d] - rmu) * rin - (double)pre_bias[d];
                acc = fma(xn, (double)wr[d], acc);
            }
#pragma unroll
            for (int o = 32; o > 0; o >>= 1) acc += __shfl_down(acc, o);
            if (lane == 0) {
                double hv = acc + (double)lat_bias[feat];
                cvalD[e] = hv;
                float hf = (float)hv;
                cref[e] = hf > 0.f ? hf : 0.f;
            }
        }
    }
    __syncthreads();
    // deterministic top-(64-g) among candidates by (value, lowest index)
    if (tid == 0) {
        const int need = KTOP - s_g;
        for (int e = 0; e < ec; ++e) csel[e] = 0;
        for (int it = 0; it < need && it < ec; ++it) {
            int best = -1; double bv = -1e300; int bidx = 1 << 30;
            for (int e = 0; e < ec; ++e) {
                if (csel[e]) continue;
                if (cvalD[e] > bv || (cvalD[e] == bv && cidx[e] < bidx)) {
                    bv = cvalD[e]; best = e; bidx = cidx[e];
                }
            }
            if (best >= 0) csel[best] = 1;
        }
    }
    __syncthreads();

    // Phase A: per-chunk keep masks (re-read, L2-hot)
    for (int i = 0; i < 64; ++i) {
        const int c = wid * 64 + i;
        const int f = c * 64 + lane;
        float val = bf2f(hr16[f]);
        bool keep;
        if (val > hi_t) keep = true;
        else if (val >= lo_t) {
            keep = false;
            for (int e = 0; e < ec; ++e)
                if (cidx[e] == f) { keep = (csel[e] != 0); break; }
        } else keep = false;
        unsigned long long bm = __ballot(keep);
        if (lane == 0) { kmask[c] = bm; ccnt[c] = (unsigned)__popcll(bm); }
    }
    __syncthreads();
    // Phase B: inclusive prefix over chunk counts
    cinc[tid] = ccnt[tid];
    __syncthreads();
#pragma unroll
    for (int o = 1; o < 256; o <<= 1) {
        unsigned t = cinc[tid] + ((tid >= o) ? cinc[tid - o] : 0u);
        __syncthreads();
        cinc[tid] = t;
        __syncthreads();
    }
    if (tid == 0) {
        unsigned tot = cinc[255];
        counts[row] = tot < 128u ? tot : 128u;
    }
    __syncthreads();
    // Phase C: masked writes
    for (int i = 0; i < 64; ++i) {
        const int c = wid * 64 + i;
        unsigned long long bm = kmask[c];
        if (!bm) continue;
        bool keep = (bm >> lane) & 1ull;
        if (keep) {
            unsigned pos = (cinc[c] - ccnt[c]) +
                           (unsigned)__popcll(bm & ((1ull << lane) - 1ull));
            if (pos < 128u) {
                const int f = c * 64 + lane;
                float sv = bf2f(hr16[f]);
                if (sv >= lo_t && sv <= hi_t) {
                    for (int e = 0; e < ec; ++e)
                        if (cidx[e] == f) { sv = cref[e]; break; }
                }
                idx_list[(size_t)row * 128 + pos] = f;
                val_list[(size_t)row * 128 + pos] = sv;
            }
        }
    }
}

// zero h_sparse region, scatter kept values, accumulate stats (round-6 proven)
__global__ __launch_bounds__(256) void k_hwrite(const unsigned* __restrict__ counts,
                                                const int* __restrict__ idx_list,
                                                const float* __restrict__ val_list,
                                                float* __restrict__ outh,
                                                unsigned* __restrict__ nnz_acc,
                                                double* __restrict__ sums) {
    const int row = blockIdx.x;
    const int tid = threadIdx.x;
    const unsigned cnt = counts[row];
    float* orow = outh + (size_t)row * Hn;
    float4* orow16 = (float4*)orow;
    const float4 z = {0.f, 0.f, 0.f, 0.f};
#pragma unroll
    for (int i = 0; i < 16; ++i) orow16[tid + i * 256] = z;
    __syncthreads();
    float val = 0.f;
    if (tid < (int)cnt) {
        int idx = idx_list[(size_t)row * 128 + tid];
        val = val_list[(size_t)row * 128 + tid];
        orow[idx] = val;
    }
    float s1 = val, s2 = val * val;
    __shared__ float r1[4], r2[4];
#pragma unroll
    for (int o = 32; o > 0; o >>= 1) {
        s1 += __shfl_down(s1, o);
        s2 += __shfl_down(s2, o);
    }
    if ((tid & 63) == 0) { r1[tid >> 6] = s1; r2[tid >> 6] = s2; }
    __syncthreads();
    if (tid == 0) {
        atomicAdd(sums + 0, (double)(r1[0] + r1[1] + r1[2] + r1[3]));
        atomicAdd(sums + 1, (double)(r2[0] + r2[1] + r2[2] + r2[3]));
        atomicAdd(nnz_acc, cnt);
    }
}

// sparse decoder: padded rows, one short8 (16B) load per thread per W row.
// Threads 0..191 (3 waves) cover 1536 elems exactly; wave 3 exits early.
__global__ __launch_bounds__(256) void k_decoder(const unsigned short* __restrict__ WdecT,
                                                 const float* __restrict__ pre_bias,
                                                 const float* __restrict__ muF,
                                                 const float* __restrict__ stdF,
                                                 const unsigned* __restrict__ counts,
                                                 const int* __restrict__ idx_list,
                                                 const float* __restrict__ val_list,
                                                 float* __restrict__ outr) {
    const int row = blockIdx.x;
    const int tid = threadIdx.x;
    const unsigned cnt = counts[row];
    __shared__ int sidx[128];
    __shared__ float sval[128];
    if (tid < (int)cnt) {
        sidx[tid] = idx_list[(size_t)row * 128 + tid];
        sval[tid] = val_list[(size_t)row * 128 + tid];
    }
    __syncthreads();
    if (tid >= 192) return;                 // no further barriers below

    float a[8] = {0.f, 0.f, 0.f, 0.f, 0.f, 0.f, 0.f, 0.f};
    float b[8] = {0.f, 0.f, 0.f, 0.f, 0.f, 0.f, 0.f, 0.f};
    const size_t toff = (size_t)tid * 8;
    unsigned j = 0;
    for (; j + 2 <= cnt; j += 2) {
        short8 w0 = *(const short8*)(WdecT + (size_t)sidx[j] * WSTR + toff);
        short8 w1 = *(const short8*)(WdecT + (size_t)sidx[j + 1] * WSTR + toff);
        const float v0 = sval[j], v1 = sval[j + 1];
#pragma unroll
        for (int i = 0; i < 8; ++i) {
            a[i] = fmaf(v0, bf2f((unsigned short)w0[i]), a[i]);
            b[i] = fmaf(v1, bf2f((unsigned short)w1[i]), b[i]);
        }
    }
    if (j < cnt) {
        short8 w0 = *(const short8*)(WdecT + (size_t)sidx[j] * WSTR + toff);
        const float v0 = sval[j];
#pragma unroll
        for (int i = 0; i < 8; ++i)
            a[i] = fmaf(v0, bf2f((unsigned short)w0[i]), a[i]);
    }
    const float m_ = muF[row], s_ = stdF[row];
    const int d0 = tid * 8;
    float o[8];
#pragma unroll
    for (int i = 0; i < 8; ++i)
        o[i] = ((a[i] + b[i]) + pre_bias[d0 + i]) * s_ + m_;
    float* orow = outr + (size_t)row * Dn + d0;
    *(float4*)(orow)     = *(float4*)&o[0];
    *(float4*)(orow + 4) = *(float4*)&o[4];
}

__global__ void k_final(const unsigned* __restrict__ nnz,
                        const double* __restrict__ sums,
                        float* __restrict__ out3) {
    if (threadIdx.x == 0) {
        const double N = (double)Bn * (double)Hn;
        const double nz = (double)(*nnz);
        const double sparsity = (N - nz) / N;
        const double mean = sums[0] / N;
        double var = (sums[1] - N * mean * mean) / (N - 1.0);
        if (var < 0.0) var = 0.0;
        out3[0] = (float)sparsity;
        out3[1] = (float)mean;
        out3[2] = (float)sqrt(var);
    }
}

extern "C" void kernel_launch(void* const* d_in, const int* in_sizes, int n_in,
                              void* d_out, int out_size, void* d_ws, size_t ws_size,
                              hipStream_t stream) {
    const float* x        = (const float*)d_in[0];
    const float* Wenc     = (const float*)d_in[1];
    const float* Wdec     = (const float*)d_in[2];
    const float* pre_bias = (const float*)d_in[3];
    const float* lat_bias = (const float*)d_in[4];

    char* ws = (char*)d_ws;
    float*          muF    = (float*)(ws + MU_OFF);
    float*          stdF   = (float*)(ws + STD_OFF);
    unsigned*       counts = (unsigned*)(ws + CNT_OFF);
    unsigned*       nnz    = (unsigned*)(ws + NNZ_OFF);
    double*         sums   = (double*)(ws + SUM_OFF);
    double*         muD    = (double*)(ws + MUD_OFF);
    double*         rinvD  = (double*)(ws + RID_OFF);
    int*            idxl   = (int*)(ws + IDX_OFF);
    float*          vall   = (float*)(ws + VAL_OFF);
    unsigned short* Ap     = (unsigned short*)(ws + AP_OFF);
    unsigned short* Bp     = (unsigned short*)(ws + BP_OFF);
    unsigned short* WdecT  = (unsigned short*)(ws + WT_OFF);
    unsigned short* h16    = (unsigned short*)(ws + H16_OFF);

    float* out       = (float*)d_out;
    float* out_recon = out;
    float* out_h     = out + (size_t)Bn * Dn;
    float* out_sc    = out + (size_t)Bn * Dn + (size_t)Bn * Hn;

    hipLaunchKernelGGL(k_zero, dim3(1), dim3(64), 0, stream, nnz, sums);
    hipLaunchKernelGGL(k_rowstats, dim3(Bn), dim3(256), 0, stream,
                       x, pre_bias, muD, rinvD, muF, stdF, Ap);
    hipLaunchKernelGGL(k_splitW, dim3(Hn), dim3(256), 0, stream, Wenc, Bp);
    hipLaunchKernelGGL(k_transpose, dim3(Hn / 32, Dn / 32), dim3(256), 0, stream, Wdec, WdecT);
    hipLaunchKernelGGL(k_gemm, dim3((Bn / 128) * (Hn / 128)), dim3(256), 0, stream,
                       Ap, Bp, lat_bias, h16);
    hipLaunchKernelGGL(k_topsel, dim3(Bn), dim3(256), 0, stream,
                       h16, x, Wenc, pre_bias, lat_bias, muD, rinvD,
                       counts, idxl, vall);
    hipLaunchKernelGGL(k_hwrite, dim3(Bn), dim3(256), 0, stream,
                       counts, idxl, vall, out_h, nnz, sums);
    hipLaunchKernelGGL(k_decoder, dim3(Bn), dim3(256), 0, stream,
                       WdecT, pre_bias, muF, stdF, counts, idxl, vall, out_recon);
    hipLaunchKernelGGL(k_final, dim3(1), dim3(64), 0, stream, nnz, sums, out_sc);
}

// Round 12
// 1456.059 us; speedup vs baseline: 4.3148x; 1.1003x over previous
//
#include <hip/hip_runtime.h>
#include <hip/hip_bf16.h>
#include <math.h>

static constexpr int Bn = 8192;
static constexpr int Hn = 16384;
static constexpr int Dn = 1536;
static constexpr int KTOP = 64;
static constexpr int KE = 1536;             // single-pass bf16 GEMM K
static constexpr int WSTR = 2048;           // padded W_decT row stride (bf16)
static constexpr double EPSD = 1e-5;

// ---- workspace byte offsets (peak ~444 MB; >=672 MB proven mapped, r1/r2) ----
static constexpr size_t MU_OFF  = 0;                 // float[8192]
static constexpr size_t STD_OFF = 32768;             // float[8192]
static constexpr size_t CNT_OFF = 98304;             // unsigned[8192]
static constexpr size_t NNZ_OFF = 131072;            // unsigned[1]
static constexpr size_t SUM_OFF = 131200;            // double[2]
static constexpr size_t MUD_OFF = 262144;            // double[8192]
static constexpr size_t RID_OFF = 327680;            // double[8192]
static constexpr size_t IDX_OFF = (size_t)1 << 20;   // int[8192*128]
static constexpr size_t VAL_OFF = (size_t)6 << 20;   // float[8192*128]
static constexpr size_t AP_OFF  = (size_t)16 << 20;  // bf16[8192*1536]   (25 MB)
static constexpr size_t BP_OFF  = (size_t)48 << 20;  // bf16[16384*1536]  (50 MB)
static constexpr size_t WT_OFF  = (size_t)104 << 20; // bf16[16384*2048]  (64 MB)
static constexpr size_t H16_OFF = (size_t)176 << 20; // bf16[8192*16384] (268 MB)

typedef __attribute__((ext_vector_type(8))) short short8;
typedef __attribute__((ext_vector_type(4))) float f32x4;

static __device__ __forceinline__ unsigned short f2bf(float f) {
    __hip_bfloat16 b = __float2bfloat16(f);
    return *reinterpret_cast<unsigned short*>(&b);
}
static __device__ __forceinline__ float bf2f(unsigned short u) {
    return __uint_as_float(((unsigned)u) << 16);
}
static __device__ __forceinline__ void gload_lds16(const void* g, void* l) {
    __builtin_amdgcn_global_load_lds(
        (const __attribute__((address_space(1))) unsigned int*)g,
        (__attribute__((address_space(3))) unsigned int*)l, 16, 0, 0);
}

__global__ void k_zero(unsigned* nnz, double* sums) {
    if (threadIdx.x == 0) { *nnz = 0u; sums[0] = 0.0; sums[1] = 0.0; }
}

// f64 row stats + write bf16 A row (xn - pre_bias) in one pass
__global__ __launch_bounds__(256) void k_rowstats(const float* __restrict__ x,
                                                  const float* __restrict__ pre_bias,
                                                  double* __restrict__ muD,
                                                  double* __restrict__ rinvD,
                                                  float* __restrict__ muF,
                                                  float* __restrict__ stdF,
                                                  unsigned short* __restrict__ Ap) {
    const int row = blockIdx.x;
    const int tid = threadIdx.x;
    const float* xr = x + (size_t)row * Dn;
    float v[6];
#pragma unroll
    for (int i = 0; i < 6; ++i) v[i] = xr[tid + 256 * i];
    double s = 0.0;
#pragma unroll
    for (int i = 0; i < 6; ++i) s += (double)v[i];
    __shared__ double redD[4];
    __shared__ double smu, srin;
#pragma unroll
    for (int o = 32; o > 0; o >>= 1) s += __shfl_down(s, o);
    if ((tid & 63) == 0) redD[tid >> 6] = s;
    __syncthreads();
    if (tid == 0) smu = (redD[0] + redD[1] + redD[2] + redD[3]) / (double)Dn;
    __syncthreads();
    const double m = smu;
    double q = 0.0;
#pragma unroll
    for (int i = 0; i < 6; ++i) { double d = (double)v[i] - m; q += d * d; }
#pragma unroll
    for (int o = 32; o > 0; o >>= 1) q += __shfl_down(q, o);
    if ((tid & 63) == 0) redD[tid >> 6] = q;
    __syncthreads();
    if (tid == 0) {
        double var = (redD[0] + redD[1] + redD[2] + redD[3]) / (double)(Dn - 1);
        double sd = sqrt(var);
        muD[row] = m;
        srin = 1.0 / (sd + EPSD);
        rinvD[row] = srin;
        muF[row] = (float)m;
        stdF[row] = (float)sd;
    }
    __syncthreads();
    const double ri = srin;
    unsigned short* ar = Ap + (size_t)row * KE;
#pragma unroll
    for (int i = 0; i < 6; ++i) {
        const int d = tid + i * 256;
        double a = ((double)v[i] - m) * ri - (double)pre_bias[d];
        ar[d] = f2bf((float)a);
    }
}

// Wenc f32 -> bf16
__global__ __launch_bounds__(256) void k_splitW(const float* __restrict__ Wenc,
                                                unsigned short* __restrict__ Bp) {
    const int row = blockIdx.x;
    const int tid = threadIdx.x;
    const float2* wr = (const float2*)(Wenc + (size_t)row * Dn);
    ushort2* br = (ushort2*)(Bp + (size_t)row * KE);
#pragma unroll
    for (int i = 0; i < 3; ++i) {
        float2 w = wr[tid + i * 256];
        ushort2 o; o.x = f2bf(w.x); o.y = f2bf(w.y);
        br[tid + i * 256] = o;
    }
}

// W_dec (D,H) f32 -> W_decT (H, stride WSTR) bf16 in ws; pads never read
__global__ __launch_bounds__(256) void k_transpose(const float* __restrict__ Wdec,
                                                   unsigned short* __restrict__ WdecT) {
    __shared__ float tile[32][33];
    const int h0 = blockIdx.x * 32;
    const int d0 = blockIdx.y * 32;
    const int tx = threadIdx.x & 31;
    const int ty = threadIdx.x >> 5;
#pragma unroll
    for (int r = 0; r < 4; ++r) {
        int d = ty + r * 8;
        tile[d][tx] = Wdec[(size_t)(d0 + d) * Hn + h0 + tx];
    }
    __syncthreads();
#pragma unroll
    for (int r = 0; r < 4; ++r) {
        int h = ty + r * 8;
        WdecT[(size_t)(h0 + h) * WSTR + d0 + tx] = f2bf(tile[tx][h]);
    }
}

// bf16 MFMA GEMM: 256x256 tile, BK=64, 8 waves (2Mx4N), per-wave C 128x64.
// Counted-vmcnt pipeline: compute tile t -> barrier -> stage t+2 into freed
// buffer -> s_waitcnt vmcnt(8) (retires exactly t+1's loads; never 0 in
// steady state) -> barrier. XOR slot-swizzle (r6-verified) on both sides.
__global__ __launch_bounds__(512, 2) void k_gemm(const unsigned short* __restrict__ Ap,
                                                 const unsigned short* __restrict__ Bp,
                                                 const float* __restrict__ lat_bias,
                                                 unsigned short* __restrict__ hout16) {
    __shared__ unsigned short AsBuf[2][256 * 64];   // 2 x 32 KB
    __shared__ unsigned short BsBuf[2][256 * 64];   // 2 x 32 KB
    const int tid = threadIdx.x;
    const int lane = tid & 63;
    const int w = tid >> 6;           // 0..7
    const int wm = w >> 2;            // 0..1
    const int wn = w & 3;             // 0..3

    const int nwg = (Bn / 256) * (Hn / 256);          // 2048, %8 == 0
    int swz = (blockIdx.x % 8) * (nwg / 8) + blockIdx.x / 8;
    int st = swz >> 6;                 // 0..31 supertiles
    int wi = swz & 63;
    int stm = st >> 3, stn = st & 7;   // 4 x 8 supertile grid
    const int bm = stm * 8 + (wi >> 3);   // 0..31
    const int bn = stn * 8 + (wi & 7);    // 0..63

    const size_t arow0 = (size_t)(bm * 256) * KE;
    const size_t brow0 = (size_t)(bn * 256) * KE;

    // staging: slice l covers idx = l*512+tid -> row = idx>>3, slot = idx&7
    #define STAGE_TILE(kt, buf)                                                   \
        {                                                                         \
            _Pragma("unroll")                                                     \
            for (int l = 0; l < 4; ++l) {                                         \
                const int idx = l * 512 + tid;                                    \
                const int row = idx >> 3, slot = idx & 7;                         \
                const int ssl = slot ^ (row & 7);                                 \
                gload_lds16(Ap + arow0 + (size_t)row * KE + (kt) * 64 + ssl * 8,  \
                            (char*)AsBuf[buf] + idx * 16);                        \
                gload_lds16(Bp + brow0 + (size_t)row * KE + (kt) * 64 + ssl * 8,  \
                            (char*)BsBuf[buf] + idx * 16);                        \
            }                                                                     \
        }

    f32x4 acc[8][4];
#pragma unroll
    for (int i = 0; i < 8; ++i)
#pragma unroll
        for (int j = 0; j < 4; ++j) acc[i][j] = (f32x4){0.f, 0.f, 0.f, 0.f};

    constexpr int NT = KE / 64;       // 24
    // prologue: stage tiles 0 and 1; wait tile 0 resident (8 newest in flight)
    STAGE_TILE(0, 0);
    STAGE_TILE(1, 1);
    asm volatile("s_waitcnt vmcnt(8)" ::: "memory");
    __builtin_amdgcn_s_barrier();
    asm volatile("" ::: "memory");

    for (int t = 0; t < NT; ++t) {
        const int buf = t & 1;
        const unsigned short* Ab = AsBuf[buf];
        const unsigned short* Bb = BsBuf[buf];
        // hold all B-frags for this tile in registers
        short8 bfr[4][2];
#pragma unroll
        for (int fj = 0; fj < 4; ++fj)
#pragma unroll
            for (int kk = 0; kk < 2; ++kk) {
                const int br = wn * 64 + fj * 16 + (lane & 15);
                const int slot = (kk * 4 + (lane >> 4)) ^ (br & 7);
                bfr[fj][kk] = *(const short8*)((const char*)Bb + br * 128 + slot * 16);
            }
#pragma unroll
        for (int qm = 0; qm < 2; ++qm) {
            short8 afr[4][2];
#pragma unroll
            for (int fi = 0; fi < 4; ++fi)
#pragma unroll
                for (int kk = 0; kk < 2; ++kk) {
                    const int ar = wm * 128 + qm * 64 + fi * 16 + (lane & 15);
                    const int slot = (kk * 4 + (lane >> 4)) ^ (ar & 7);
                    afr[fi][kk] = *(const short8*)((const char*)Ab + ar * 128 + slot * 16);
                }
#pragma unroll
            for (int kk = 0; kk < 2; ++kk)
#pragma unroll
                for (int fi = 0; fi < 4; ++fi)
#pragma unroll
                    for (int fj = 0; fj < 4; ++fj)
                        acc[qm * 4 + fi][fj] = __builtin_amdgcn_mfma_f32_16x16x32_bf16(
                            afr[fi][kk], bfr[fj][kk], acc[qm * 4 + fi][fj], 0, 0, 0);
        }
        __builtin_amdgcn_s_barrier();          // all waves done reading buf
        asm volatile("" ::: "memory");
        if (t + 2 < NT) {
            STAGE_TILE(t + 2, buf);            // buf is free now
            asm volatile("s_waitcnt vmcnt(8)" ::: "memory");   // t+1 resident
        } else {
            asm volatile("s_waitcnt vmcnt(0)" ::: "memory");
        }
        __builtin_amdgcn_s_barrier();          // publish t+1 to all waves
        asm volatile("" ::: "memory");
    }
    #undef STAGE_TILE

    // epilogue: C/D map col=lane&15, row=(lane>>4)*4+reg  [m89]
    const int col = lane & 15;
#pragma unroll
    for (int fj = 0; fj < 4; ++fj) {
        const int gn = bn * 256 + wn * 64 + fj * 16 + col;
        const float bias = lat_bias[gn];
#pragma unroll
        for (int fi8 = 0; fi8 < 8; ++fi8) {
            const int gm0 = bm * 256 + wm * 128 + fi8 * 16 + (lane >> 4) * 4;
#pragma unroll
            for (int r = 0; r < 4; ++r) {
                float vv = acc[fi8][fj][r] + bias;
                hout16[(size_t)(gm0 + r) * Hn + gn] = f2bf(fmaxf(vv, 0.f));
            }
        }
    }
}

// FUSED: bisect threshold (registers) + classify (registers) + f64 band refine
// + deterministic selection + 3-phase compaction. One h16 HBM sweep total.
__global__ __launch_bounds__(256) void k_topsel(const unsigned short* __restrict__ h16,
                                                const float* __restrict__ x,
                                                const float* __restrict__ Wenc,
                                                const float* __restrict__ pre_bias,
                                                const float* __restrict__ lat_bias,
                                                const double* __restrict__ muD,
                                                const double* __restrict__ rinvD,
                                                unsigned* __restrict__ counts,
                                                int* __restrict__ idx_list,
                                                float* __restrict__ val_list) {
    const int row = blockIdx.x;
    const int tid = threadIdx.x;
    const int lane = tid & 63;
    const int wid = tid >> 6;
    const unsigned short* hr16 = h16 + (size_t)row * Hn;
    const unsigned* hu = (const unsigned*)hr16;
    unsigned u[32];
#pragma unroll
    for (int j = 0; j < 32; ++j) u[j] = hu[j * 256 + tid];

    __shared__ int wsum[4];
    __shared__ unsigned sbc;
    unsigned lo = 0, hi = 0xFFFFu;
    while (lo < hi) {
        const unsigned mid = (lo + hi + 1) >> 1;
        int c = 0;
#pragma unroll
        for (int j = 0; j < 32; ++j) {
            c += ((u[j] & 0xFFFFu) >= mid) ? 1 : 0;
            c += ((u[j] >> 16) >= mid) ? 1 : 0;
        }
#pragma unroll
        for (int o = 32; o > 0; o >>= 1) c += __shfl_down(c, o);
        if ((tid & 63) == 0) wsum[tid >> 6] = c;
        __syncthreads();
        if (tid == 0) sbc = (unsigned)(wsum[0] + wsum[1] + wsum[2] + wsum[3]);
        __syncthreads();
        if (sbc >= (unsigned)KTOP) lo = mid; else hi = mid - 1;
    }
    const float thr = bf2f((unsigned short)lo);
    const float DELTA = 0.02f;
    const float hi_t = thr + DELTA;
    const float lo_t = thr - DELTA;

    constexpr int MAXC = 128;
    __shared__ int s_g, s_c;
    __shared__ int cidx[MAXC];
    __shared__ double cvalD[MAXC];
    __shared__ float cref[MAXC];
    __shared__ unsigned char csel[MAXC];
    __shared__ unsigned long long kmask[256];
    __shared__ unsigned ccnt[256];
    __shared__ unsigned cinc[256];
    if (tid == 0) { s_g = 0; s_c = 0; }
    __syncthreads();
    int g_loc = 0;
#pragma unroll
    for (int j = 0; j < 32; ++j) {
        float v0 = bf2f((unsigned short)(u[j] & 0xFFFFu));
        float v1 = bf2f((unsigned short)(u[j] >> 16));
        const int i0 = 2 * (j * 256 + tid);
        if (v0 > hi_t) g_loc++;
        else if (v0 >= lo_t) {
            int p = atomicAdd(&s_c, 1);
            if (p < MAXC) cidx[p] = i0;
        }
        if (v1 > hi_t) g_loc++;
        else if (v1 >= lo_t) {
            int p = atomicAdd(&s_c, 1);
            if (p < MAXC) cidx[p] = i0 + 1;
        }
    }
    if (g_loc) atomicAdd(&s_g, g_loc);
    __syncthreads();
    const int ec = (s_c < MAXC) ? s_c : MAXC;

    {
        const double rmu = muD[row];
        const double rin = rinvD[row];
        const float* xr = x + (size_t)row * Dn;
        for (int e = wid; e < ec; e += 4) {
            const int feat = cidx[e];
            const float* wr = Wenc + (size_t)feat * Dn;
            double acc = 0.0;
            for (int d = lane; d < Dn; d += 64) {
                double xn = ((double)xr[d] - rmu) * rin - (double)pre_bias[d];
                acc = fma(xn, (double)wr[d], acc);
            }
#pragma unroll
            for (int o = 32; o > 0; o >>= 1) acc += __shfl_down(acc, o);
            if (lane == 0) {
                double hv = acc + (double)lat_bias[feat];
                cvalD[e] = hv;
                float hf = (float)hv;
                cref[e] = hf > 0.f ? hf : 0.f;
            }
        }
    }
    __syncthreads();
    if (tid == 0) {
        const int need = KTOP - s_g;
        for (int e = 0; e < ec; ++e) csel[e] = 0;
        for (int it = 0; it < need && it < ec; ++it) {
            int best = -1; double bv = -1e300; int bidx = 1 << 30;
            for (int e = 0; e < ec; ++e) {
                if (csel[e]) continue;
                if (cvalD[e] > bv || (cvalD[e] == bv && cidx[e] < bidx)) {
                    bv = cvalD[e]; best = e; bidx = cidx[e];
                }
            }
            if (best >= 0) csel[best] = 1;
        }
    }
    __syncthreads();

    for (int i = 0; i < 64; ++i) {
        const int c = wid * 64 + i;
        const int f = c * 64 + lane;
        float val = bf2f(hr16[f]);
        bool keep;
        if (val > hi_t) keep = true;
        else if (val >= lo_t) {
            keep = false;
            for (int e = 0; e < ec; ++e)
                if (cidx[e] == f) { keep = (csel[e] != 0); break; }
        } else keep = false;
        unsigned long long bm = __ballot(keep);
        if (lane == 0) { kmask[c] = bm; ccnt[c] = (unsigned)__popcll(bm); }
    }
    __syncthreads();
    cinc[tid] = ccnt[tid];
    __syncthreads();
#pragma unroll
    for (int o = 1; o < 256; o <<= 1) {
        unsigned t = cinc[tid] + ((tid >= o) ? cinc[tid - o] : 0u);
        __syncthreads();
        cinc[tid] = t;
        __syncthreads();
    }
    if (tid == 0) {
        unsigned tot = cinc[255];
        counts[row] = tot < 128u ? tot : 128u;
    }
    __syncthreads();
    for (int i = 0; i < 64; ++i) {
        const int c = wid * 64 + i;
        unsigned long long bm = kmask[c];
        if (!bm) continue;
        bool keep = (bm >> lane) & 1ull;
        if (keep) {
            unsigned pos = (cinc[c] - ccnt[c]) +
                           (unsigned)__popcll(bm & ((1ull << lane) - 1ull));
            if (pos < 128u) {
                const int f = c * 64 + lane;
                float sv = bf2f(hr16[f]);
                if (sv >= lo_t && sv <= hi_t) {
                    for (int e = 0; e < ec; ++e)
                        if (cidx[e] == f) { sv = cref[e]; break; }
                }
                idx_list[(size_t)row * 128 + pos] = f;
                val_list[(size_t)row * 128 + pos] = sv;
            }
        }
    }
}

// zero h_sparse region, scatter kept values, accumulate stats (round-6 proven)
__global__ __launch_bounds__(256) void k_hwrite(const unsigned* __restrict__ counts,
                                                const int* __restrict__ idx_list,
                                                const float* __restrict__ val_list,
                                                float* __restrict__ outh,
                                                unsigned* __restrict__ nnz_acc,
                                                double* __restrict__ sums) {
    const int row = blockIdx.x;
    const int tid = threadIdx.x;
    const unsigned cnt = counts[row];
    float* orow = outh + (size_t)row * Hn;
    float4* orow16 = (float4*)orow;
    const float4 z = {0.f, 0.f, 0.f, 0.f};
#pragma unroll
    for (int i = 0; i < 16; ++i) orow16[tid + i * 256] = z;
    __syncthreads();
    float val = 0.f;
    if (tid < (int)cnt) {
        int idx = idx_list[(size_t)row * 128 + tid];
        val = val_list[(size_t)row * 128 + tid];
        orow[idx] = val;
    }
    float s1 = val, s2 = val * val;
    __shared__ float r1[4], r2[4];
#pragma unroll
    for (int o = 32; o > 0; o >>= 1) {
        s1 += __shfl_down(s1, o);
        s2 += __shfl_down(s2, o);
    }
    if ((tid & 63) == 0) { r1[tid >> 6] = s1; r2[tid >> 6] = s2; }
    __syncthreads();
    if (tid == 0) {
        atomicAdd(sums + 0, (double)(r1[0] + r1[1] + r1[2] + r1[3]));
        atomicAdd(sums + 1, (double)(r2[0] + r2[1] + r2[2] + r2[3]));
        atomicAdd(nnz_acc, cnt);
    }
}

// sparse decoder: padded rows, one short8 (16B) load per thread per W row.
__global__ __launch_bounds__(256) void k_decoder(const unsigned short* __restrict__ WdecT,
                                                 const float* __restrict__ pre_bias,
                                                 const float* __restrict__ muF,
                                                 const float* __restrict__ stdF,
                                                 const unsigned* __restrict__ counts,
                                                 const int* __restrict__ idx_list,
                                                 const float* __restrict__ val_list,
                                                 float* __restrict__ outr) {
    const int row = blockIdx.x;
    const int tid = threadIdx.x;
    const unsigned cnt = counts[row];
    __shared__ int sidx[128];
    __shared__ float sval[128];
    if (tid < (int)cnt) {
        sidx[tid] = idx_list[(size_t)row * 128 + tid];
        sval[tid] = val_list[(size_t)row * 128 + tid];
    }
    __syncthreads();
    if (tid >= 192) return;

    float a[8] = {0.f, 0.f, 0.f, 0.f, 0.f, 0.f, 0.f, 0.f};
    float b[8] = {0.f, 0.f, 0.f, 0.f, 0.f, 0.f, 0.f, 0.f};
    const size_t toff = (size_t)tid * 8;
    unsigned j = 0;
    for (; j + 2 <= cnt; j += 2) {
        short8 w0 = *(const short8*)(WdecT + (size_t)sidx[j] * WSTR + toff);
        short8 w1 = *(const short8*)(WdecT + (size_t)sidx[j + 1] * WSTR + toff);
        const float v0 = sval[j], v1 = sval[j + 1];
#pragma unroll
        for (int i = 0; i < 8; ++i) {
            a[i] = fmaf(v0, bf2f((unsigned short)w0[i]), a[i]);
            b[i] = fmaf(v1, bf2f((unsigned short)w1[i]), b[i]);
        }
    }
    if (j < cnt) {
        short8 w0 = *(const short8*)(WdecT + (size_t)sidx[j] * WSTR + toff);
        const float v0 = sval[j];
#pragma unroll
        for (int i = 0; i < 8; ++i)
            a[i] = fmaf(v0, bf2f((unsigned short)w0[i]), a[i]);
    }
    const float m_ = muF[row], s_ = stdF[row];
    const int d0 = tid * 8;
    float o[8];
#pragma unroll
    for (int i = 0; i < 8; ++i)
        o[i] = ((a[i] + b[i]) + pre_bias[d0 + i]) * s_ + m_;
    float* orow = outr + (size_t)row * Dn + d0;
    *(float4*)(orow)     = *(float4*)&o[0];
    *(float4*)(orow + 4) = *(float4*)&o[4];
}

__global__ void k_final(const unsigned* __restrict__ nnz,
                        const double* __restrict__ sums,
                        float* __restrict__ out3) {
    if (threadIdx.x == 0) {
        const double N = (double)Bn * (double)Hn;
        const double nz = (double)(*nnz);
        const double sparsity = (N - nz) / N;
        const double mean = sums[0] / N;
        double var = (sums[1] - N * mean * mean) / (N - 1.0);
        if (var < 0.0) var = 0.0;
        out3[0] = (float)sparsity;
        out3[1] = (float)mean;
        out3[2] = (float)sqrt(var);
    }
}

extern "C" void kernel_launch(void* const* d_in, const int* in_sizes, int n_in,
                              void* d_out, int out_size, void* d_ws, size_t ws_size,
                              hipStream_t stream) {
    const float* x        = (const float*)d_in[0];
    const float* Wenc     = (const float*)d_in[1];
    const float* Wdec     = (const float*)d_in[2];
    const float* pre_bias = (const float*)d_in[3];
    const float* lat_bias = (const float*)d_in[4];

    char* ws = (char*)d_ws;
    float*          muF    = (float*)(ws + MU_OFF);
    float*          stdF   = (float*)(ws + STD_OFF);
    unsigned*       counts = (unsigned*)(ws + CNT_OFF);
    unsigned*       nnz    = (unsigned*)(ws + NNZ_OFF);
    double*         sums   = (double*)(ws + SUM_OFF);
    double*         muD    = (double*)(ws + MUD_OFF);
    double*         rinvD  = (double*)(ws + RID_OFF);
    int*            idxl   = (int*)(ws + IDX_OFF);
    float*          vall   = (float*)(ws + VAL_OFF);
    unsigned short* Ap     = (unsigned short*)(ws + AP_OFF);
    unsigned short* Bp     = (unsigned short*)(ws + BP_OFF);
    unsigned short* WdecT  = (unsigned short*)(ws + WT_OFF);
    unsigned short* h16    = (unsigned short*)(ws + H16_OFF);

    float* out       = (float*)d_out;
    float* out_recon = out;
    float* out_h     = out + (size_t)Bn * Dn;
    float* out_sc    = out + (size_t)Bn * Dn + (size_t)Bn * Hn;

    hipLaunchKernelGGL(k_zero, dim3(1), dim3(64), 0, stream, nnz, sums);
    hipLaunchKernelGGL(k_rowstats, dim3(Bn), dim3(256), 0, stream,
                       x, pre_bias, muD, rinvD, muF, stdF, Ap);
    hipLaunchKernelGGL(k_splitW, dim3(Hn), dim3(256), 0, stream, Wenc, Bp);
    hipLaunchKernelGGL(k_transpose, dim3(Hn / 32, Dn / 32), dim3(256), 0, stream, Wdec, WdecT);
    hipLaunchKernelGGL(k_gemm, dim3((Bn / 256) * (Hn / 256)), dim3(512), 0, stream,
                       Ap, Bp, lat_bias, h16);
    hipLaunchKernelGGL(k_topsel, dim3(Bn), dim3(256), 0, stream,
                       h16, x, Wenc, pre_bias, lat_bias, muD, rinvD,
                       counts, idxl, vall);
    hipLaunchKernelGGL(k_hwrite, dim3(Bn), dim3(256), 0, stream,
                       counts, idxl, vall, out_h, nnz, sums);
    hipLaunchKernelGGL(k_decoder, dim3(Bn), dim3(256), 0, stream,
                       WdecT, pre_bias, muF, stdF, counts, idxl, vall, out_recon);
    hipLaunchKernelGGL(k_final, dim3(1), dim3(64), 0, stream, nnz, sums, out_sc);
}